// Round 5
// baseline (3401.487 us; speedup 1.0000x reference)
//
#include <hip/hip_runtime.h>
#include <cstdint>
#include <cmath>

#define B_ 2
#define T_ 2048
#define C_ 2048
#define H_ 32
#define BT_ (B_ * T_)
#define BTC_ ((size_t)B_ * T_ * C_)

typedef __attribute__((ext_vector_type(4))) float f32x4;
typedef __attribute__((ext_vector_type(8))) short bf16x8;
typedef __attribute__((ext_vector_type(4))) unsigned short us4;
typedef __attribute__((ext_vector_type(4))) int i32x4;

__device__ __forceinline__ unsigned short f2bf(float f) {
  union { float f; unsigned int u; } c; c.f = f;
  unsigned int u = c.u;
  return (unsigned short)((u + 0x7FFFu + ((u >> 16) & 1u)) >> 16);
}
__device__ __forceinline__ float bf2f(unsigned short h) {
  union { unsigned int u; float f; } c; c.u = ((unsigned int)h) << 16;
  return c.f;
}
__device__ __forceinline__ float rlane(float v, int lane) {
  return __int_as_float(__builtin_amdgcn_readlane(__float_as_int(v), lane));
}
__device__ __forceinline__ void split4(f32x4 v, us4& h, us4& l) {
  h.x = f2bf(v.x); l.x = f2bf(v.x - bf2f(h.x));
  h.y = f2bf(v.y); l.y = f2bf(v.y - bf2f(h.y));
  h.z = f2bf(v.z); l.z = f2bf(v.z - bf2f(h.z));
  h.w = f2bf(v.w); l.w = f2bf(v.w - bf2f(h.w));
}

// ---------------- token shift + mixes: r/k/v as bf16 hi+lo pairs, w/a/g bf16 ----------------
__global__ __launch_bounds__(256) void k_mix(
    const float* __restrict__ x, const float* __restrict__ shift,
    const float* __restrict__ m_r, const float* __restrict__ m_w,
    const float* __restrict__ m_k, const float* __restrict__ m_v,
    const float* __restrict__ m_a, const float* __restrict__ m_g,
    unsigned short* __restrict__ r_h, unsigned short* __restrict__ r_l,
    unsigned short* __restrict__ k_h, unsigned short* __restrict__ k_l,
    unsigned short* __restrict__ v_h, unsigned short* __restrict__ v_l,
    unsigned short* __restrict__ o_w, unsigned short* __restrict__ o_a,
    unsigned short* __restrict__ o_g,
    float* __restrict__ xlast) {
  size_t i4 = ((size_t)blockIdx.x * 256 + threadIdx.x) * 4;
  int c = (int)(i4 % C_);
  size_t bt = i4 / C_;
  int t = (int)(bt % T_);
  int b = (int)(bt / T_);
  f32x4 xv = *(const f32x4*)(x + i4);
  f32x4 pv = (t == 0) ? *(const f32x4*)(shift + (size_t)b * C_ + c)
                      : *(const f32x4*)(x + i4 - C_);
  f32x4 dx = pv - xv;
#define MIXHL(mp, oh, ol) { f32x4 mm = *(const f32x4*)(mp + c); f32x4 rr = xv + dx * mm; \
    us4 hh, ll; split4(rr, hh, ll); *(us4*)(oh + i4) = hh; *(us4*)(ol + i4) = ll; }
#define MIXH(mp, oh) { f32x4 mm = *(const f32x4*)(mp + c); f32x4 rr = xv + dx * mm; \
    us4 pk; pk.x = f2bf(rr.x); pk.y = f2bf(rr.y); pk.z = f2bf(rr.z); pk.w = f2bf(rr.w); \
    *(us4*)(oh + i4) = pk; }
  MIXHL(m_r, r_h, r_l) MIXHL(m_k, k_h, k_l) MIXHL(m_v, v_h, v_l)
  MIXH(m_w, o_w) MIXH(m_a, o_a) MIXH(m_g, o_g)
#undef MIXHL
#undef MIXH
  if (t == T_ - 1) *(f32x4*)(xlast + (size_t)b * C_ + c) = xv;
}

// ---------------- f32 [R][Cc] -> bf16 [Cc][R] transpose ----------------
__global__ __launch_bounds__(256) void k_tr(const float* __restrict__ in,
                                            unsigned short* __restrict__ out,
                                            int R, int Cc) {
  __shared__ float tile[32][33];
  int c0 = blockIdx.x * 32, r0 = blockIdx.y * 32;
  int tid = threadIdx.x;
  int rr = tid >> 3, c4 = (tid & 7) * 4;
  f32x4 v = *(const f32x4*)(in + (size_t)(r0 + rr) * Cc + c0 + c4);
  tile[rr][c4] = v.x; tile[rr][c4 + 1] = v.y; tile[rr][c4 + 2] = v.z; tile[rr][c4 + 3] = v.w;
  __syncthreads();
  int cc = tid >> 3, r4 = (tid & 7) * 4;
  us4 o;
  o.x = f2bf(tile[r4][cc]); o.y = f2bf(tile[r4 + 1][cc]);
  o.z = f2bf(tile[r4 + 2][cc]); o.w = f2bf(tile[r4 + 3][cc]);
  *(us4*)(out + (size_t)(c0 + cc) * R + r0 + r4) = o;
}

// ---------------- f32 [R][Cc] -> bf16 hi+lo [Cc][R] split transpose ----------------
__global__ __launch_bounds__(256) void k_trs(const float* __restrict__ in,
                                             unsigned short* __restrict__ oh,
                                             unsigned short* __restrict__ ol,
                                             int R, int Cc) {
  __shared__ float tile[32][33];
  int c0 = blockIdx.x * 32, r0 = blockIdx.y * 32;
  int tid = threadIdx.x;
  int rr = tid >> 3, c4 = (tid & 7) * 4;
  f32x4 v = *(const f32x4*)(in + (size_t)(r0 + rr) * Cc + c0 + c4);
  tile[rr][c4] = v.x; tile[rr][c4 + 1] = v.y; tile[rr][c4 + 2] = v.z; tile[rr][c4 + 3] = v.w;
  __syncthreads();
  int cc = tid >> 3, r4 = (tid & 7) * 4;
  f32x4 w = { tile[r4][cc], tile[r4 + 1][cc], tile[r4 + 2][cc], tile[r4 + 3][cc] };
  us4 h, l; split4(w, h, l);
  size_t o = (size_t)(c0 + cc) * R + r0 + r4;
  *(us4*)(oh + o) = h; *(us4*)(ol + o) = l;
}

// ---------------- bf16 GEMM: C[M,N] = X[M,K] @ Wt[N,K]^T ----------------
// mode: 0 = f32 store, 1 = bf16 store, 2 = tanh->bf16, 3 = sigmoid->bf16
__global__ __launch_bounds__(256) void k_gemm(
    const unsigned short* __restrict__ X, const unsigned short* __restrict__ Wt,
    void* __restrict__ out, int M, int N, int K, int mode) {
  __shared__ alignas(16) unsigned short As[128 * 32];
  __shared__ alignas(16) unsigned short Bs[128 * 32];
  const int tid = threadIdx.x;
  const int lane = tid & 63, wave = tid >> 6;
  const int wr = wave >> 1, wc = wave & 1;
  const int lm = lane & 15, lq = lane >> 4;
  const int m0 = blockIdx.y * 128, n0 = blockIdx.x * 128;
  const int srow = (lane >> 2);
  const int kcol = (lane & 3) * 8;
  f32x4 acc[4][4];
#pragma unroll
  for (int i = 0; i < 4; ++i)
#pragma unroll
    for (int j = 0; j < 4; ++j) acc[i][j] = (f32x4){0.f, 0.f, 0.f, 0.f};

  for (int k0 = 0; k0 < K; k0 += 32) {
#pragma unroll
    for (int p = 0; p < 2; ++p) {
      int row = wave * 32 + p * 16 + srow;
      i32x4 d = *(const i32x4*)(X + (size_t)(m0 + row) * K + k0 + kcol);
      *(i32x4*)(As + (size_t)(wave * 2 + p) * 512 + lane * 8) = d;
    }
#pragma unroll
    for (int p = 0; p < 2; ++p) {
      int row = wave * 32 + p * 16 + srow;
      int n = n0 + row; if (n > N - 1) n = N - 1;
      i32x4 d = *(const i32x4*)(Wt + (size_t)n * K + k0 + kcol);
      *(i32x4*)(Bs + (size_t)(wave * 2 + p) * 512 + lane * 8) = d;
    }
    __syncthreads();
    bf16x8 af[4], bfr[4];
#pragma unroll
    for (int i = 0; i < 4; ++i)
      af[i] = *(const bf16x8*)(As + (size_t)(wr * 64 + i * 16 + lm) * 32 + lq * 8);
#pragma unroll
    for (int j = 0; j < 4; ++j)
      bfr[j] = *(const bf16x8*)(Bs + (size_t)(wc * 64 + j * 16 + lm) * 32 + lq * 8);
#pragma unroll
    for (int i = 0; i < 4; ++i)
#pragma unroll
      for (int j = 0; j < 4; ++j)
        acc[i][j] = __builtin_amdgcn_mfma_f32_16x16x32_bf16(af[i], bfr[j], acc[i][j], 0, 0, 0);
    __syncthreads();
  }
#pragma unroll
  for (int i = 0; i < 4; ++i)
#pragma unroll
    for (int j = 0; j < 4; ++j) {
      int n = n0 + wc * 64 + j * 16 + lm;
      if (n >= N) continue;
      int mb = m0 + wr * 64 + i * 16 + lq * 4;
#pragma unroll
      for (int r = 0; r < 4; ++r) {
        float val = acc[i][j][r];
        size_t off = (size_t)(mb + r) * N + n;
        if (mode == 0) {
          ((float*)out)[off] = val;
        } else {
          if (mode == 2) val = tanhf(val);
          else if (mode == 3) val = 1.0f / (1.0f + __expf(-val));
          ((unsigned short*)out)[off] = f2bf(val);
        }
      }
    }
}

// ---------------- split (hi+lo) bf16 GEMM: near-f32 product precision ----------------
// acc += Ah*Bh [+ Al*Bh if xlo] [+ Ah*Bl if wlo] [+ Al*Bl if xlo&&wlo]
__global__ __launch_bounds__(256) void k_gemm2(
    const unsigned short* __restrict__ Xh, const unsigned short* __restrict__ Xl, int xlo,
    const unsigned short* __restrict__ Wh, const unsigned short* __restrict__ Wl, int wlo,
    void* __restrict__ out, int M, int N, int K, int mode) {
  __shared__ alignas(16) unsigned short Ah[128 * 32];
  __shared__ alignas(16) unsigned short Al[128 * 32];
  __shared__ alignas(16) unsigned short Bh[128 * 32];
  __shared__ alignas(16) unsigned short Bl[128 * 32];
  const int tid = threadIdx.x;
  const int lane = tid & 63, wave = tid >> 6;
  const int wr = wave >> 1, wc = wave & 1;
  const int lm = lane & 15, lq = lane >> 4;
  const int m0 = blockIdx.y * 128, n0 = blockIdx.x * 128;
  const int srow = (lane >> 2);
  const int kcol = (lane & 3) * 8;
  f32x4 acc[4][4];
#pragma unroll
  for (int i = 0; i < 4; ++i)
#pragma unroll
    for (int j = 0; j < 4; ++j) acc[i][j] = (f32x4){0.f, 0.f, 0.f, 0.f};

  for (int k0 = 0; k0 < K; k0 += 32) {
#pragma unroll
    for (int p = 0; p < 2; ++p) {
      int row = wave * 32 + p * 16 + srow;
      int off = (wave * 2 + p) * 512 + lane * 8;
      size_t ga = (size_t)(m0 + row) * K + k0 + kcol;
      *(i32x4*)(Ah + off) = *(const i32x4*)(Xh + ga);
      if (xlo) *(i32x4*)(Al + off) = *(const i32x4*)(Xl + ga);
      int n = n0 + row; if (n > N - 1) n = N - 1;
      size_t gb = (size_t)n * K + k0 + kcol;
      *(i32x4*)(Bh + off) = *(const i32x4*)(Wh + gb);
      if (wlo) *(i32x4*)(Bl + off) = *(const i32x4*)(Wl + gb);
    }
    __syncthreads();
    bf16x8 ah[4], bh[4];
#pragma unroll
    for (int i = 0; i < 4; ++i)
      ah[i] = *(const bf16x8*)(Ah + (size_t)(wr * 64 + i * 16 + lm) * 32 + lq * 8);
#pragma unroll
    for (int j = 0; j < 4; ++j)
      bh[j] = *(const bf16x8*)(Bh + (size_t)(wc * 64 + j * 16 + lm) * 32 + lq * 8);
#pragma unroll
    for (int i = 0; i < 4; ++i)
#pragma unroll
      for (int j = 0; j < 4; ++j)
        acc[i][j] = __builtin_amdgcn_mfma_f32_16x16x32_bf16(ah[i], bh[j], acc[i][j], 0, 0, 0);
    if (xlo) {
      bf16x8 al[4];
#pragma unroll
      for (int i = 0; i < 4; ++i)
        al[i] = *(const bf16x8*)(Al + (size_t)(wr * 64 + i * 16 + lm) * 32 + lq * 8);
#pragma unroll
      for (int i = 0; i < 4; ++i)
#pragma unroll
        for (int j = 0; j < 4; ++j)
          acc[i][j] = __builtin_amdgcn_mfma_f32_16x16x32_bf16(al[i], bh[j], acc[i][j], 0, 0, 0);
      if (wlo) {
        bf16x8 bl[4];
#pragma unroll
        for (int j = 0; j < 4; ++j)
          bl[j] = *(const bf16x8*)(Bl + (size_t)(wc * 64 + j * 16 + lm) * 32 + lq * 8);
#pragma unroll
        for (int i = 0; i < 4; ++i)
#pragma unroll
          for (int j = 0; j < 4; ++j) {
            acc[i][j] = __builtin_amdgcn_mfma_f32_16x16x32_bf16(ah[i], bl[j], acc[i][j], 0, 0, 0);
            acc[i][j] = __builtin_amdgcn_mfma_f32_16x16x32_bf16(al[i], bl[j], acc[i][j], 0, 0, 0);
          }
      }
    } else if (wlo) {
      bf16x8 bl[4];
#pragma unroll
      for (int j = 0; j < 4; ++j)
        bl[j] = *(const bf16x8*)(Bl + (size_t)(wc * 64 + j * 16 + lm) * 32 + lq * 8);
#pragma unroll
      for (int i = 0; i < 4; ++i)
#pragma unroll
        for (int j = 0; j < 4; ++j)
          acc[i][j] = __builtin_amdgcn_mfma_f32_16x16x32_bf16(ah[i], bl[j], acc[i][j], 0, 0, 0);
    }
    __syncthreads();
  }
#pragma unroll
  for (int i = 0; i < 4; ++i)
#pragma unroll
    for (int j = 0; j < 4; ++j) {
      int n = n0 + wc * 64 + j * 16 + lm;
      if (n >= N) continue;
      int mb = m0 + wr * 64 + i * 16 + lq * 4;
#pragma unroll
      for (int r = 0; r < 4; ++r) {
        float val = acc[i][j][r];
        size_t off = (size_t)(mb + r) * N + n;
        if (mode == 0) {
          ((float*)out)[off] = val;
        } else {
          if (mode == 2) val = tanhf(val);
          else if (mode == 3) val = 1.0f / (1.0f + __expf(-val));
          ((unsigned short*)out)[off] = f2bf(val);
        }
      }
    }
}

// ---------------- pre-scan fused elementwise (one wave per (b,t,h)) ----------------
__global__ __launch_bounds__(256) void k_pre(
    const float* __restrict__ rp, const float* __restrict__ kp, float* __restrict__ vp,
    const unsigned short* __restrict__ ww, const unsigned short* __restrict__ aa,
    const unsigned short* __restrict__ vv,
    const float* __restrict__ vfirst,
    const float* __restrict__ w0, const float* __restrict__ a0, const float* __restrict__ v0,
    const float* __restrict__ kkc, const float* __restrict__ kac,
    const float* __restrict__ rkw,
    unsigned short* __restrict__ rb, unsigned short* __restrict__ wb,
    unsigned short* __restrict__ kb, unsigned short* __restrict__ vb,
    unsigned short* __restrict__ ab, unsigned short* __restrict__ bb,
    float* __restrict__ dp) {
  int gw = blockIdx.x * 4 + (threadIdx.x >> 6);
  int l = threadIdx.x & 63;
  int h = gw & (H_ - 1);
  size_t bt = (size_t)(gw >> 5);
  size_t idx = bt * C_ + h * 64 + l;
  int c = h * 64 + l;
  float rf = rp[idx], kf = kp[idx], vr = vp[idx];
  float z = -(w0[c] + bf2f(ww[idx]));
  float sp = (z > 15.f) ? z : log1pf(__expf(z));
  float wv = -sp - 0.5f;
  float ag = 1.f / (1.f + __expf(-(a0[c] + bf2f(aa[idx]))));
  float sv = 1.f / (1.f + __expf(-(v0[c] + bf2f(vv[idx]))));
  float vf = vr + (vfirst[idx] - vr) * sv;
  float kkv = kf * kkc[c];   // kk from PRE-modification k
  float ss = kkv * kkv;
#pragma unroll
  for (int m = 1; m < 64; m <<= 1) ss += __shfl_xor(ss, m);
  float nrm = fmaxf(sqrtf(ss), 1e-12f);
  float kkn = kkv / nrm;
  float ks = kf * (1.f + (ag - 1.f) * kac[c]);
  vp[idx] = vf;
  float bon = rf * ks * rkw[c];
#pragma unroll
  for (int m = 1; m < 64; m <<= 1) bon += __shfl_xor(bon, m);
  if (l == 0) dp[bt * H_ + h] = bon;
  rb[idx] = f2bf(rf); wb[idx] = f2bf(wv); kb[idx] = f2bf(ks);
  vb[idx] = f2bf(vf); ab[idx] = f2bf(-kkn); bb[idx] = f2bf(kkn * ag);
}

// ---------------- delta-rule scan: one block per (b,h), state in registers ----------------
__global__ __launch_bounds__(256) void k_scan(
    const unsigned short* __restrict__ rb, const unsigned short* __restrict__ wb,
    const unsigned short* __restrict__ kb, const unsigned short* __restrict__ vb,
    const unsigned short* __restrict__ ab, const unsigned short* __restrict__ bb,
    const float* __restrict__ s0, float* __restrict__ o, float* __restrict__ sout) {
  const int bh = blockIdx.x;
  const int l = threadIdx.x & 63, kg = threadIdx.x >> 6;
  const int b = bh >> 5, h = bh & (H_ - 1);
  float S[16];
  size_t sbase = (size_t)bh * 64 * 64;
#pragma unroll
  for (int i = 0; i < 16; ++i) S[i] = s0[sbase + (size_t)(kg * 16 + i) * 64 + l];
  __shared__ float Pps[256], Ppo[256];
  size_t base = (size_t)b * ((size_t)T_ * C_) + h * 64 + l;
  float pr[4], pw[4], pk[4], pv[4], pa[4], pb[4];
#pragma unroll
  for (int s = 0; s < 4; ++s) {
    size_t a_ = base + (size_t)s * C_;
    pr[s] = bf2f(rb[a_]); pw[s] = bf2f(wb[a_]); pk[s] = bf2f(kb[a_]);
    pv[s] = bf2f(vb[a_]); pa[s] = bf2f(ab[a_]); pb[s] = bf2f(bb[a_]);
  }
  for (int t0 = 0; t0 < T_; t0 += 4) {
#pragma unroll
    for (int u = 0; u < 4; ++u) {
      const int t = t0 + u;
      float rl = pr[u], wl = pw[u], kl = pk[u], vl = pv[u], al = pa[u], bl = pb[u];
      if (t + 4 < T_) {
        size_t a_ = base + (size_t)(t + 4) * C_;
        pr[u] = bf2f(rb[a_]); pw[u] = bf2f(wb[a_]); pk[u] = bf2f(kb[a_]);
        pv[u] = bf2f(vb[a_]); pa[u] = bf2f(ab[a_]); pb[u] = bf2f(bb[a_]);
      }
      float ewl = exp2f(wl * 1.4426950408889634f);
      float ps = 0.f;
#pragma unroll
      for (int i = 0; i < 16; ++i) ps = fmaf(rlane(al, kg * 16 + i), S[i], ps);
      Pps[kg * 64 + l] = ps;
      __syncthreads();
      float sa = Pps[l] + Pps[64 + l] + Pps[128 + l] + Pps[192 + l];
      float po = 0.f;
#pragma unroll
      for (int i = 0; i < 16; ++i) {
        int kk = kg * 16 + i;
        float ewk = rlane(ewl, kk), bk = rlane(bl, kk), kkv = rlane(kl, kk), rk = rlane(rl, kk);
        S[i] = fmaf(S[i], ewk, fmaf(bk, sa, kkv * vl));
        po = fmaf(rk, S[i], po);
      }
      Ppo[kg * 64 + l] = po;
      __syncthreads();
      if (kg == 0) o[base + (size_t)t * C_] = Ppo[l] + Ppo[64 + l] + Ppo[128 + l] + Ppo[192 + l];
    }
  }
#pragma unroll
  for (int i = 0; i < 16; ++i) sout[sbase + (size_t)(kg * 16 + i) * 64 + l] = S[i];
}

// ---------------- post-scan: GroupNorm + bonus + *g -> bf16 ----------------
__global__ __launch_bounds__(256) void k_post(
    const float* __restrict__ o, const float* __restrict__ vp, const float* __restrict__ gp,
    const float* __restrict__ dp,
    const float* __restrict__ lnw, const float* __restrict__ lnb,
    unsigned short* __restrict__ z) {
  int gw = blockIdx.x * 4 + (threadIdx.x >> 6);
  int l = threadIdx.x & 63;
  int h = gw & (H_ - 1);
  size_t bt = (size_t)(gw >> 5);
  size_t idx = bt * C_ + h * 64 + l;
  int c = h * 64 + l;
  float ov = o[idx];
  float s1 = ov;
#pragma unroll
  for (int m = 1; m < 64; m <<= 1) s1 += __shfl_xor(s1, m);
  float mu = s1 * (1.f / 64.f);
  float d = ov - mu;
  float s2 = d * d;
#pragma unroll
  for (int m = 1; m < 64; m <<= 1) s2 += __shfl_xor(s2, m);
  float var = s2 * (1.f / 64.f);
  float y = d * rsqrtf(var + 6.4e-4f);   // EPS_GN = 1e-5 * 8^2
  y = y * lnw[c] + lnb[c];
  y = fmaf(dp[bt * H_ + h], vp[idx], y);
  z[idx] = f2bf(y * gp[idx]);
}

extern "C" void kernel_launch(void* const* d_in, const int* in_sizes, int n_in,
                              void* d_out, int out_size, void* d_ws, size_t ws_size,
                              hipStream_t stream) {
  const float* x      = (const float*)d_in[0];
  const float* shift  = (const float*)d_in[1];
  const float* wkv    = (const float*)d_in[2];
  const float* vfirst = (const float*)d_in[3];
  const float* x_r    = (const float*)d_in[4];
  const float* x_w    = (const float*)d_in[5];
  const float* x_k    = (const float*)d_in[6];
  const float* x_v    = (const float*)d_in[7];
  const float* x_a    = (const float*)d_in[8];
  const float* x_g    = (const float*)d_in[9];
  const float* w0     = (const float*)d_in[10];
  const float* w1     = (const float*)d_in[11];
  const float* w2     = (const float*)d_in[12];
  const float* a0     = (const float*)d_in[13];
  const float* a1     = (const float*)d_in[14];
  const float* a2     = (const float*)d_in[15];
  const float* v0     = (const float*)d_in[16];
  const float* v1     = (const float*)d_in[17];
  const float* v2     = (const float*)d_in[18];
  const float* g1     = (const float*)d_in[19];
  const float* g2     = (const float*)d_in[20];
  const float* k_k    = (const float*)d_in[21];
  const float* k_a    = (const float*)d_in[22];
  const float* r_k    = (const float*)d_in[23];
  const float* W_r    = (const float*)d_in[24];
  const float* W_k    = (const float*)d_in[25];
  const float* W_v    = (const float*)d_in[26];
  const float* W_o    = (const float*)d_in[27];
  const float* ln_w   = (const float*)d_in[28];
  const float* ln_b   = (const float*)d_in[29];

  // ---- workspace plan: ~213 MiB (< 221 MiB proven footprint) ----
  char* wp = (char*)d_ws;
  auto alloc = [&](size_t bytes) { char* p = wp; wp += (bytes + 255) & ~(size_t)255; return p; };
  const size_t SB = BTC_ * 2;   // bf16 BTC (16 MiB)
  const size_t SF = BTC_ * 4;   // f32 BTC (32 MiB)

  unsigned short* w1t = (unsigned short*)alloc((size_t)C_ * 64 * 2);
  unsigned short* w2t = (unsigned short*)alloc((size_t)C_ * 64 * 2);
  unsigned short* a1t = (unsigned short*)alloc((size_t)C_ * 64 * 2);
  unsigned short* a2t = (unsigned short*)alloc((size_t)C_ * 64 * 2);
  unsigned short* v1t = (unsigned short*)alloc((size_t)C_ * 32 * 2);
  unsigned short* v2t = (unsigned short*)alloc((size_t)C_ * 32 * 2);
  unsigned short* g1t = (unsigned short*)alloc((size_t)C_ * 128 * 2);
  unsigned short* g2t = (unsigned short*)alloc((size_t)C_ * 128 * 2);
  unsigned short* hw  = (unsigned short*)alloc((size_t)BT_ * 64 * 2);
  unsigned short* ha  = (unsigned short*)alloc((size_t)BT_ * 64 * 2);
  unsigned short* hv  = (unsigned short*)alloc((size_t)BT_ * 32 * 2);
  unsigned short* hg  = (unsigned short*)alloc((size_t)BT_ * 128 * 2);
  unsigned short* Wt2 = (unsigned short*)alloc((size_t)C_ * C_ * 2 * 2); // hi | lo
  float* dp           = (float*)alloc((size_t)BT_ * H_ * 4);
  unsigned short* xw  = (unsigned short*)alloc(SB);   // w-mix -> ww -> scan wb (in place)
  unsigned short* xa  = (unsigned short*)alloc(SB);   // a-mix -> aa -> scan ab
  unsigned short* xg  = (unsigned short*)alloc(SB);   // g-mix -> vv -> scan bb
  unsigned short* xr2 = (unsigned short*)alloc(2 * SB); // r-mix hi|lo -> k f32 -> z bf16
  unsigned short* xk2 = (unsigned short*)alloc(2 * SB); // k-mix hi|lo -> v f32 (blended)
  unsigned short* xv2 = (unsigned short*)alloc(2 * SB); // v-mix hi|lo -> scan rb|kb
  float* rbuf         = (float*)alloc(SF);             // r f32 -> g f32
  unsigned short* vbb = (unsigned short*)alloc(SB);    // scan vb

  unsigned short* Wh = Wt2;
  unsigned short* Wl = Wt2 + (size_t)C_ * C_;
  unsigned short* xr_h = xr2, *xr_l = xr2 + BTC_;
  unsigned short* xk_h = xk2, *xk_l = xk2 + BTC_;
  unsigned short* xv_h = xv2, *xv_l = xv2 + BTC_;
  float* kbuf = (float*)xr2;            // after r GEMM, xr2 dead
  float* vbuf = (float*)xk2;            // after k GEMM, xk2 dead
  unsigned short* rb = xv2;             // after v GEMM, xv2 dead
  unsigned short* kb = xv2 + BTC_;
  float* gfull = rbuf;                  // after k_pre
  unsigned short* zbuf = (unsigned short*)xr2;  // after k_pre (k f32 dead)

  float* outp  = (float*)d_out;
  float* xlast = outp + BTC_;
  float* soutp = outp + BTC_ + (size_t)B_ * C_;
  float* obuf  = outp;   // scan o in d_out[0:BTC), dead before final GEMM writes outp

  auto tr = [&](const float* in, unsigned short* out, int R, int Cc) {
    k_tr<<<dim3(Cc / 32, R / 32), 256, 0, stream>>>(in, out, R, Cc);
  };
  auto gemm = [&](const unsigned short* X, const unsigned short* Wtp, void* out,
                  int M, int N, int K, int mode) {
    k_gemm<<<dim3((N + 127) / 128, M / 128), 256, 0, stream>>>(X, Wtp, out, M, N, K, mode);
  };
  auto gemm2 = [&](const unsigned short* Xh_, const unsigned short* Xl_, int xlo,
                   const unsigned short* Wh_, const unsigned short* Wl_, int wlo,
                   void* out, int M, int N, int K, int mode) {
    k_gemm2<<<dim3((N + 127) / 128, M / 128), 256, 0, stream>>>(Xh_, Xl_, xlo, Wh_, Wl_, wlo,
                                                                out, M, N, K, mode);
  };

  k_mix<<<(int)(BTC_ / 4 / 256), 256, 0, stream>>>(x, shift, x_r, x_w, x_k, x_v, x_a, x_g,
                                                   xr_h, xr_l, xk_h, xk_l, xv_h, xv_l,
                                                   xw, xa, xg, xlast);
  tr(w1, w1t, C_, 64);  tr(w2, w2t, 64, C_);
  tr(a1, a1t, C_, 64);  tr(a2, a2t, 64, C_);
  tr(v1, v1t, C_, 32);  tr(v2, v2t, 32, C_);
  tr(g1, g1t, C_, 128); tr(g2, g2t, 128, C_);

  // LoRA stage 1
  gemm(xw, w1t, hw, BT_, 64, C_, 2);                      // tanh
  gemm(xa, a1t, ha, BT_, 64, C_, 1);
  gemm2(xv_h, xv_l, 1, v1t, nullptr, 0, hv, BT_, 32, C_, 1);
  gemm(xg, g1t, hg, BT_, 128, C_, 3);                     // sigmoid

  // big projections, split precision (matches ref f32 GEMM to ~1e-6)
  k_trs<<<dim3(C_ / 32, C_ / 32), 256, 0, stream>>>(W_r, Wh, Wl, C_, C_);
  gemm2(xr_h, xr_l, 1, Wh, Wl, 1, rbuf, BT_, C_, C_, 0);
  k_trs<<<dim3(C_ / 32, C_ / 32), 256, 0, stream>>>(W_k, Wh, Wl, C_, C_);
  gemm2(xk_h, xk_l, 1, Wh, Wl, 1, kbuf, BT_, C_, C_, 0);
  k_trs<<<dim3(C_ / 32, C_ / 32), 256, 0, stream>>>(W_v, Wh, Wl, C_, C_);
  gemm2(xv_h, xv_l, 1, Wh, Wl, 1, vbuf, BT_, C_, C_, 0);

  // LoRA stage 2 into the dead mix buffers
  gemm(hw, w2t, xw, BT_, C_, 64, 1);   // ww
  gemm(ha, a2t, xa, BT_, C_, 64, 1);   // aa
  gemm(hv, v2t, xg, BT_, C_, 32, 1);   // vv

  // scan operands: rb->xv2[0], wb->xw (in place), kb->xv2[1], vb->vbb, ab->xa, bb->xg
  k_pre<<<BT_ * H_ / 4, 256, 0, stream>>>(rbuf, kbuf, vbuf, xw, xa, xg, vfirst,
                                          w0, a0, v0, k_k, k_a, r_k,
                                          rb, xw, kb, vbb, xa, xg, dp);

  gemm(hg, g2t, gfull, BT_, C_, 128, 0);  // g f32 into dead rbuf

  k_scan<<<B_ * H_, 256, 0, stream>>>(rb, xw, kb, vbb, xa, xg, wkv, obuf, soutp);

  k_post<<<BT_ * H_ / 4, 256, 0, stream>>>(obuf, vbuf, gfull, dp, ln_w, ln_b, zbuf);

  k_trs<<<dim3(C_ / 32, C_ / 32), 256, 0, stream>>>(W_o, Wh, Wl, C_, C_);
  gemm(zbuf, Wh, outp, BT_, C_, C_, 0);
}

// Round 6
// 1961.036 us; speedup vs baseline: 1.7345x; 1.7345x over previous
//
#include <hip/hip_runtime.h>
#include <cstdint>
#include <cmath>

#define B_ 2
#define T_ 2048
#define C_ 2048
#define H_ 32
#define BT_ (B_ * T_)
#define BTC_ ((size_t)B_ * T_ * C_)
#define L_ 128
#define NC_ 16

typedef __attribute__((ext_vector_type(4))) float f32x4;
typedef __attribute__((ext_vector_type(2))) float f32x2;
typedef __attribute__((ext_vector_type(8))) short bf16x8;
typedef __attribute__((ext_vector_type(4))) unsigned short us4;
typedef __attribute__((ext_vector_type(4))) int i32x4;

__device__ __forceinline__ unsigned short f2bf(float f) {
  union { float f; unsigned int u; } c; c.f = f;
  unsigned int u = c.u;
  return (unsigned short)((u + 0x7FFFu + ((u >> 16) & 1u)) >> 16);
}
__device__ __forceinline__ float bf2f(unsigned short h) {
  union { unsigned int u; float f; } c; c.u = ((unsigned int)h) << 16;
  return c.f;
}
__device__ __forceinline__ float rlane(float v, int lane) {
  return __int_as_float(__builtin_amdgcn_readlane(__float_as_int(v), lane));
}
__device__ __forceinline__ void split4(f32x4 v, us4& h, us4& l) {
  h.x = f2bf(v.x); l.x = f2bf(v.x - bf2f(h.x));
  h.y = f2bf(v.y); l.y = f2bf(v.y - bf2f(h.y));
  h.z = f2bf(v.z); l.z = f2bf(v.z - bf2f(h.z));
  h.w = f2bf(v.w); l.w = f2bf(v.w - bf2f(h.w));
}

// ---------------- token shift + mixes: r/k/v as bf16 hi+lo pairs, w/a/g bf16 ----------------
__global__ __launch_bounds__(256) void k_mix(
    const float* __restrict__ x, const float* __restrict__ shift,
    const float* __restrict__ m_r, const float* __restrict__ m_w,
    const float* __restrict__ m_k, const float* __restrict__ m_v,
    const float* __restrict__ m_a, const float* __restrict__ m_g,
    unsigned short* __restrict__ r_h, unsigned short* __restrict__ r_l,
    unsigned short* __restrict__ k_h, unsigned short* __restrict__ k_l,
    unsigned short* __restrict__ v_h, unsigned short* __restrict__ v_l,
    unsigned short* __restrict__ o_w, unsigned short* __restrict__ o_a,
    unsigned short* __restrict__ o_g,
    float* __restrict__ xlast) {
  size_t i4 = ((size_t)blockIdx.x * 256 + threadIdx.x) * 4;
  int c = (int)(i4 % C_);
  size_t bt = i4 / C_;
  int t = (int)(bt % T_);
  int b = (int)(bt / T_);
  f32x4 xv = *(const f32x4*)(x + i4);
  f32x4 pv = (t == 0) ? *(const f32x4*)(shift + (size_t)b * C_ + c)
                      : *(const f32x4*)(x + i4 - C_);
  f32x4 dx = pv - xv;
#define MIXHL(mp, oh, ol) { f32x4 mm = *(const f32x4*)(mp + c); f32x4 rr = xv + dx * mm; \
    us4 hh, ll; split4(rr, hh, ll); *(us4*)(oh + i4) = hh; *(us4*)(ol + i4) = ll; }
#define MIXH(mp, oh) { f32x4 mm = *(const f32x4*)(mp + c); f32x4 rr = xv + dx * mm; \
    us4 pk; pk.x = f2bf(rr.x); pk.y = f2bf(rr.y); pk.z = f2bf(rr.z); pk.w = f2bf(rr.w); \
    *(us4*)(oh + i4) = pk; }
  MIXHL(m_r, r_h, r_l) MIXHL(m_k, k_h, k_l) MIXHL(m_v, v_h, v_l)
  MIXH(m_w, o_w) MIXH(m_a, o_a) MIXH(m_g, o_g)
#undef MIXHL
#undef MIXH
  if (t == T_ - 1) *(f32x4*)(xlast + (size_t)b * C_ + c) = xv;
}

// ---------------- f32 [R][Cc] -> bf16 [Cc][R] transpose ----------------
__global__ __launch_bounds__(256) void k_tr(const float* __restrict__ in,
                                            unsigned short* __restrict__ out,
                                            int R, int Cc) {
  __shared__ float tile[32][33];
  int c0 = blockIdx.x * 32, r0 = blockIdx.y * 32;
  int tid = threadIdx.x;
  int rr = tid >> 3, c4 = (tid & 7) * 4;
  f32x4 v = *(const f32x4*)(in + (size_t)(r0 + rr) * Cc + c0 + c4);
  tile[rr][c4] = v.x; tile[rr][c4 + 1] = v.y; tile[rr][c4 + 2] = v.z; tile[rr][c4 + 3] = v.w;
  __syncthreads();
  int cc = tid >> 3, r4 = (tid & 7) * 4;
  us4 o;
  o.x = f2bf(tile[r4][cc]); o.y = f2bf(tile[r4 + 1][cc]);
  o.z = f2bf(tile[r4 + 2][cc]); o.w = f2bf(tile[r4 + 3][cc]);
  *(us4*)(out + (size_t)(c0 + cc) * R + r0 + r4) = o;
}

// ---------------- f32 [R][Cc] -> bf16 hi+lo [Cc][R] split transpose ----------------
__global__ __launch_bounds__(256) void k_trs(const float* __restrict__ in,
                                             unsigned short* __restrict__ oh,
                                             unsigned short* __restrict__ ol,
                                             int R, int Cc) {
  __shared__ float tile[32][33];
  int c0 = blockIdx.x * 32, r0 = blockIdx.y * 32;
  int tid = threadIdx.x;
  int rr = tid >> 3, c4 = (tid & 7) * 4;
  f32x4 v = *(const f32x4*)(in + (size_t)(r0 + rr) * Cc + c0 + c4);
  tile[rr][c4] = v.x; tile[rr][c4 + 1] = v.y; tile[rr][c4 + 2] = v.z; tile[rr][c4 + 3] = v.w;
  __syncthreads();
  int cc = tid >> 3, r4 = (tid & 7) * 4;
  f32x4 w = { tile[r4][cc], tile[r4 + 1][cc], tile[r4 + 2][cc], tile[r4 + 3][cc] };
  us4 h, l; split4(w, h, l);
  size_t o = (size_t)(c0 + cc) * R + r0 + r4;
  *(us4*)(oh + o) = h; *(us4*)(ol + o) = l;
}

// ---------------- bf16 GEMM: C[M,N] = X[M,K] @ Wt[N,K]^T ----------------
__global__ __launch_bounds__(256) void k_gemm(
    const unsigned short* __restrict__ X, const unsigned short* __restrict__ Wt,
    void* __restrict__ out, int M, int N, int K, int mode) {
  __shared__ alignas(16) unsigned short As[128 * 32];
  __shared__ alignas(16) unsigned short Bs[128 * 32];
  const int tid = threadIdx.x;
  const int lane = tid & 63, wave = tid >> 6;
  const int wr = wave >> 1, wc = wave & 1;
  const int lm = lane & 15, lq = lane >> 4;
  const int m0 = blockIdx.y * 128, n0 = blockIdx.x * 128;
  const int srow = (lane >> 2);
  const int kcol = (lane & 3) * 8;
  f32x4 acc[4][4];
#pragma unroll
  for (int i = 0; i < 4; ++i)
#pragma unroll
    for (int j = 0; j < 4; ++j) acc[i][j] = (f32x4){0.f, 0.f, 0.f, 0.f};

  for (int k0 = 0; k0 < K; k0 += 32) {
#pragma unroll
    for (int p = 0; p < 2; ++p) {
      int row = wave * 32 + p * 16 + srow;
      i32x4 d = *(const i32x4*)(X + (size_t)(m0 + row) * K + k0 + kcol);
      *(i32x4*)(As + (size_t)(wave * 2 + p) * 512 + lane * 8) = d;
    }
#pragma unroll
    for (int p = 0; p < 2; ++p) {
      int row = wave * 32 + p * 16 + srow;
      int n = n0 + row; if (n > N - 1) n = N - 1;
      i32x4 d = *(const i32x4*)(Wt + (size_t)n * K + k0 + kcol);
      *(i32x4*)(Bs + (size_t)(wave * 2 + p) * 512 + lane * 8) = d;
    }
    __syncthreads();
    bf16x8 af[4], bfr[4];
#pragma unroll
    for (int i = 0; i < 4; ++i)
      af[i] = *(const bf16x8*)(As + (size_t)(wr * 64 + i * 16 + lm) * 32 + lq * 8);
#pragma unroll
    for (int j = 0; j < 4; ++j)
      bfr[j] = *(const bf16x8*)(Bs + (size_t)(wc * 64 + j * 16 + lm) * 32 + lq * 8);
#pragma unroll
    for (int i = 0; i < 4; ++i)
#pragma unroll
      for (int j = 0; j < 4; ++j)
        acc[i][j] = __builtin_amdgcn_mfma_f32_16x16x32_bf16(af[i], bfr[j], acc[i][j], 0, 0, 0);
    __syncthreads();
  }
#pragma unroll
  for (int i = 0; i < 4; ++i)
#pragma unroll
    for (int j = 0; j < 4; ++j) {
      int n = n0 + wc * 64 + j * 16 + lm;
      if (n >= N) continue;
      int mb = m0 + wr * 64 + i * 16 + lq * 4;
#pragma unroll
      for (int r = 0; r < 4; ++r) {
        float val = acc[i][j][r];
        size_t off = (size_t)(mb + r) * N + n;
        if (mode == 0) {
          ((float*)out)[off] = val;
        } else {
          if (mode == 2) val = tanhf(val);
          else if (mode == 3) val = 1.0f / (1.0f + __expf(-val));
          ((unsigned short*)out)[off] = f2bf(val);
        }
      }
    }
}

// ---------------- split (hi+lo) bf16 GEMM ----------------
__global__ __launch_bounds__(256) void k_gemm2(
    const unsigned short* __restrict__ Xh, const unsigned short* __restrict__ Xl, int xlo,
    const unsigned short* __restrict__ Wh, const unsigned short* __restrict__ Wl, int wlo,
    void* __restrict__ out, int M, int N, int K, int mode) {
  __shared__ alignas(16) unsigned short Ah[128 * 32];
  __shared__ alignas(16) unsigned short Al[128 * 32];
  __shared__ alignas(16) unsigned short Bh[128 * 32];
  __shared__ alignas(16) unsigned short Bl[128 * 32];
  const int tid = threadIdx.x;
  const int lane = tid & 63, wave = tid >> 6;
  const int wr = wave >> 1, wc = wave & 1;
  const int lm = lane & 15, lq = lane >> 4;
  const int m0 = blockIdx.y * 128, n0 = blockIdx.x * 128;
  const int srow = (lane >> 2);
  const int kcol = (lane & 3) * 8;
  f32x4 acc[4][4];
#pragma unroll
  for (int i = 0; i < 4; ++i)
#pragma unroll
    for (int j = 0; j < 4; ++j) acc[i][j] = (f32x4){0.f, 0.f, 0.f, 0.f};

  for (int k0 = 0; k0 < K; k0 += 32) {
#pragma unroll
    for (int p = 0; p < 2; ++p) {
      int row = wave * 32 + p * 16 + srow;
      int off = (wave * 2 + p) * 512 + lane * 8;
      size_t ga = (size_t)(m0 + row) * K + k0 + kcol;
      *(i32x4*)(Ah + off) = *(const i32x4*)(Xh + ga);
      if (xlo) *(i32x4*)(Al + off) = *(const i32x4*)(Xl + ga);
      int n = n0 + row; if (n > N - 1) n = N - 1;
      size_t gb = (size_t)n * K + k0 + kcol;
      *(i32x4*)(Bh + off) = *(const i32x4*)(Wh + gb);
      if (wlo) *(i32x4*)(Bl + off) = *(const i32x4*)(Wl + gb);
    }
    __syncthreads();
    bf16x8 ah[4], bh[4];
#pragma unroll
    for (int i = 0; i < 4; ++i)
      ah[i] = *(const bf16x8*)(Ah + (size_t)(wr * 64 + i * 16 + lm) * 32 + lq * 8);
#pragma unroll
    for (int j = 0; j < 4; ++j)
      bh[j] = *(const bf16x8*)(Bh + (size_t)(wc * 64 + j * 16 + lm) * 32 + lq * 8);
#pragma unroll
    for (int i = 0; i < 4; ++i)
#pragma unroll
      for (int j = 0; j < 4; ++j)
        acc[i][j] = __builtin_amdgcn_mfma_f32_16x16x32_bf16(ah[i], bh[j], acc[i][j], 0, 0, 0);
    if (xlo) {
      bf16x8 al[4];
#pragma unroll
      for (int i = 0; i < 4; ++i)
        al[i] = *(const bf16x8*)(Al + (size_t)(wr * 64 + i * 16 + lm) * 32 + lq * 8);
#pragma unroll
      for (int i = 0; i < 4; ++i)
#pragma unroll
        for (int j = 0; j < 4; ++j)
          acc[i][j] = __builtin_amdgcn_mfma_f32_16x16x32_bf16(al[i], bh[j], acc[i][j], 0, 0, 0);
      if (wlo) {
        bf16x8 bl[4];
#pragma unroll
        for (int j = 0; j < 4; ++j)
          bl[j] = *(const bf16x8*)(Bl + (size_t)(wc * 64 + j * 16 + lm) * 32 + lq * 8);
#pragma unroll
        for (int i = 0; i < 4; ++i)
#pragma unroll
          for (int j = 0; j < 4; ++j) {
            acc[i][j] = __builtin_amdgcn_mfma_f32_16x16x32_bf16(ah[i], bl[j], acc[i][j], 0, 0, 0);
            acc[i][j] = __builtin_amdgcn_mfma_f32_16x16x32_bf16(al[i], bl[j], acc[i][j], 0, 0, 0);
          }
      }
    } else if (wlo) {
      bf16x8 bl[4];
#pragma unroll
      for (int j = 0; j < 4; ++j)
        bl[j] = *(const bf16x8*)(Bl + (size_t)(wc * 64 + j * 16 + lm) * 32 + lq * 8);
#pragma unroll
      for (int i = 0; i < 4; ++i)
#pragma unroll
        for (int j = 0; j < 4; ++j)
          acc[i][j] = __builtin_amdgcn_mfma_f32_16x16x32_bf16(ah[i], bl[j], acc[i][j], 0, 0, 0);
    }
    __syncthreads();
  }
#pragma unroll
  for (int i = 0; i < 4; ++i)
#pragma unroll
    for (int j = 0; j < 4; ++j) {
      int n = n0 + wc * 64 + j * 16 + lm;
      if (n >= N) continue;
      int mb = m0 + wr * 64 + i * 16 + lq * 4;
#pragma unroll
      for (int r = 0; r < 4; ++r) {
        float val = acc[i][j][r];
        size_t off = (size_t)(mb + r) * N + n;
        if (mode == 0) {
          ((float*)out)[off] = val;
        } else {
          if (mode == 2) val = tanhf(val);
          else if (mode == 3) val = 1.0f / (1.0f + __expf(-val));
          ((unsigned short*)out)[off] = f2bf(val);
        }
      }
    }
}

// ---------------- pre-scan fused elementwise ----------------
__global__ __launch_bounds__(256) void k_pre(
    const float* __restrict__ rp, const float* __restrict__ kp, float* __restrict__ vp,
    const unsigned short* __restrict__ ww, const unsigned short* __restrict__ aa,
    const unsigned short* __restrict__ vv,
    const float* __restrict__ vfirst,
    const float* __restrict__ w0, const float* __restrict__ a0, const float* __restrict__ v0,
    const float* __restrict__ kkc, const float* __restrict__ kac,
    const float* __restrict__ rkw,
    unsigned short* __restrict__ rb, unsigned short* __restrict__ wb,
    unsigned short* __restrict__ kb, unsigned short* __restrict__ vb,
    unsigned short* __restrict__ ab, unsigned short* __restrict__ bb,
    float* __restrict__ dp) {
  int gw = blockIdx.x * 4 + (threadIdx.x >> 6);
  int l = threadIdx.x & 63;
  int h = gw & (H_ - 1);
  size_t bt = (size_t)(gw >> 5);
  size_t idx = bt * C_ + h * 64 + l;
  int c = h * 64 + l;
  float rf = rp[idx], kf = kp[idx], vr = vp[idx];
  float z = -(w0[c] + bf2f(ww[idx]));
  float sp = (z > 15.f) ? z : log1pf(__expf(z));
  float wv = -sp - 0.5f;
  float ag = 1.f / (1.f + __expf(-(a0[c] + bf2f(aa[idx]))));
  float sv = 1.f / (1.f + __expf(-(v0[c] + bf2f(vv[idx]))));
  float vf = vr + (vfirst[idx] - vr) * sv;
  float kkv = kf * kkc[c];
  float ss = kkv * kkv;
#pragma unroll
  for (int m = 1; m < 64; m <<= 1) ss += __shfl_xor(ss, m);
  float nrm = fmaxf(sqrtf(ss), 1e-12f);
  float kkn = kkv / nrm;
  float ks = kf * (1.f + (ag - 1.f) * kac[c]);
  vp[idx] = vf;
  float bon = rf * ks * rkw[c];
#pragma unroll
  for (int m = 1; m < 64; m <<= 1) bon += __shfl_xor(bon, m);
  if (l == 0) dp[bt * H_ + h] = bon;
  rb[idx] = f2bf(rf); wb[idx] = f2bf(wv); kb[idx] = f2bf(ks);
  vb[idx] = f2bf(vf); ab[idx] = f2bf(-kkn); bb[idx] = f2bf(kkn * ag);
}

// ================= chunk-parallel scan =================
// Pass 1: per (b,h,chunk) compute P = prod A_t (stored TRANSPOSED) and U.
__global__ __launch_bounds__(256) void k_scanP(
    const unsigned short* __restrict__ wb, const unsigned short* __restrict__ kb,
    const unsigned short* __restrict__ vb, const unsigned short* __restrict__ ab,
    const unsigned short* __restrict__ bb,
    float* __restrict__ Pg, float* __restrict__ Ug) {
  const int blk = blockIdx.x;
  const int c = blk & (NC_ - 1), bh = blk >> 4;
  const int b = bh >> 5, h = bh & (H_ - 1);
  const int l = threadIdx.x & 63;
  const int kg = __builtin_amdgcn_readfirstlane(threadIdx.x >> 6);
  const int kg16 = kg * 16;
  __shared__ f32x2 part[2][256];
  size_t base = (size_t)b * ((size_t)T_ * C_) + (size_t)(c * L_) * C_ + h * 64 + l;
  float P[16], U[16];
#pragma unroll
  for (int i = 0; i < 16; ++i) { P[i] = (kg16 + i == l) ? 1.f : 0.f; U[i] = 0.f; }
  float pw[4], pk[4], pv[4], pa[4], pb[4];
#pragma unroll
  for (int s = 0; s < 4; ++s) {
    size_t a_ = base + (size_t)s * C_;
    pw[s] = bf2f(wb[a_]); pk[s] = bf2f(kb[a_]); pv[s] = bf2f(vb[a_]);
    pa[s] = bf2f(ab[a_]); pb[s] = bf2f(bb[a_]);
  }
  float saP = pa[0];      // a0^T I = a0
  float saU = 0.f;
  for (int t0 = 0; t0 < L_; t0 += 4) {
#pragma unroll
    for (int u = 0; u < 4; ++u) {
      const int t = t0 + u;
      float wl = pw[u], kl = pk[u], vl = pv[u], bl = pb[u];
      float an = pa[(u + 1) & 3];          // a(t+1)
      if (t + 4 < L_) {
        size_t a_ = base + (size_t)(t + 4) * C_;
        pw[u] = bf2f(wb[a_]); pk[u] = bf2f(kb[a_]); pv[u] = bf2f(vb[a_]);
        pa[u] = bf2f(ab[a_]); pb[u] = bf2f(bb[a_]);
      }
      float ew = exp2f(wl * 1.4426950408889634f);
      float psP = 0.f, psU = 0.f;
#pragma unroll
      for (int i = 0; i < 16; ++i) {
        int ki = kg16 + i;
        float ewk = rlane(ew, ki), bk = rlane(bl, ki), kk = rlane(kl, ki);
        P[i] = fmaf(P[i], ewk, bk * saP);
        U[i] = fmaf(U[i], ewk, fmaf(bk, saU, kk * vl));
        float ak = rlane(an, ki);
        psP = fmaf(ak, P[i], psP);
        psU = fmaf(ak, U[i], psU);
      }
      part[t & 1][kg * 64 + l] = (f32x2){psP, psU};
      __syncthreads();
      f32x2 q0 = part[t & 1][l], q1 = part[t & 1][64 + l],
            q2 = part[t & 1][128 + l], q3 = part[t & 1][192 + l];
      saP = (q0.x + q1.x) + (q2.x + q3.x);
      saU = (q0.y + q1.y) + (q2.y + q3.y);
    }
  }
  size_t pb_ = (size_t)blk * 4096;
#pragma unroll
  for (int i = 0; i < 16; ++i) {
    Pg[pb_ + (size_t)l * 64 + kg16 + i] = P[i];   // transposed: Pt[j][r]
    Ug[pb_ + (size_t)(kg16 + i) * 64 + l] = U[i]; // normal: U[r][v]
  }
}

// Pass 2: sequential chunk combine per (b,h): S_{c+1} = P_c S_c + U_c; saves S_c.
__global__ __launch_bounds__(256) void k_scanC(
    const float* __restrict__ Pg, const float* __restrict__ Ug,
    const float* __restrict__ s0, float* __restrict__ Scg, float* __restrict__ sout) {
  const int bh = blockIdx.x;
  const int l = threadIdx.x & 63;
  const int kg = __builtin_amdgcn_readfirstlane(threadIdx.x >> 6);
  const int kg16 = kg * 16;
  const int tid = threadIdx.x;
  __shared__ float Sb[4096];
  // init S from s0
#pragma unroll
  for (int q = 0; q < 4; ++q) {
    int e = tid * 16 + q * 4;
    *(f32x4*)(Sb + e) = *(const f32x4*)(s0 + (size_t)bh * 4096 + e);
  }
  __syncthreads();
  for (int c = 0; c < NC_; ++c) {
    size_t cb = ((size_t)bh * NC_ + c) * 4096;
    // save S_c
#pragma unroll
    for (int q = 0; q < 4; ++q) {
      int e = tid * 16 + q * 4;
      *(f32x4*)(Scg + cb + e) = *(const f32x4*)(Sb + e);
    }
    const float* Pt = Pg + cb;
    const float* Uc = Ug + cb;
    float acc[16];
#pragma unroll
    for (int i = 0; i < 16; ++i) acc[i] = Uc[(size_t)(kg16 + i) * 64 + l];
    for (int j = 0; j < 64; ++j) {
      float s = Sb[j * 64 + l];
#pragma unroll
      for (int i = 0; i < 16; ++i) acc[i] = fmaf(Pt[j * 64 + kg16 + i], s, acc[i]);
    }
    __syncthreads();
#pragma unroll
    for (int i = 0; i < 16; ++i) Sb[(kg16 + i) * 64 + l] = acc[i];
    __syncthreads();
  }
#pragma unroll
  for (int q = 0; q < 4; ++q) {
    int e = tid * 16 + q * 4;
    *(f32x4*)(sout + (size_t)bh * 4096 + e) = *(const f32x4*)(Sb + e);
  }
}

// Pass 3: replay each chunk from exact S_{c,0}, emit o.
__global__ __launch_bounds__(256) void k_scanR(
    const unsigned short* __restrict__ rb, const unsigned short* __restrict__ wb,
    const unsigned short* __restrict__ kb, const unsigned short* __restrict__ vb,
    const unsigned short* __restrict__ ab, const unsigned short* __restrict__ bb,
    const float* __restrict__ Scg, float* __restrict__ o) {
  const int blk = blockIdx.x;
  const int c = blk & (NC_ - 1), bh = blk >> 4;
  const int b = bh >> 5, h = bh & (H_ - 1);
  const int l = threadIdx.x & 63;
  const int kg = __builtin_amdgcn_readfirstlane(threadIdx.x >> 6);
  const int kg16 = kg * 16;
  __shared__ f32x2 part[2][256];
  size_t base = (size_t)b * ((size_t)T_ * C_) + (size_t)(c * L_) * C_ + h * 64 + l;
  float S[16];
  size_t cb = (size_t)blk * 4096;
#pragma unroll
  for (int i = 0; i < 16; ++i) S[i] = Scg[cb + (size_t)(kg16 + i) * 64 + l];
  float pr[4], pw[4], pk[4], pv[4], pa[4], pb[4];
#pragma unroll
  for (int s = 0; s < 4; ++s) {
    size_t a_ = base + (size_t)s * C_;
    pr[s] = bf2f(rb[a_]); pw[s] = bf2f(wb[a_]); pk[s] = bf2f(kb[a_]);
    pv[s] = bf2f(vb[a_]); pa[s] = bf2f(ab[a_]); pb[s] = bf2f(bb[a_]);
  }
  // pre-iteration: sa(0) = a0^T S_c0
  {
    float ps = 0.f;
#pragma unroll
    for (int i = 0; i < 16; ++i) ps = fmaf(rlane(pa[0], kg16 + i), S[i], ps);
    part[0][kg * 64 + l] = (f32x2){0.f, ps};
  }
  __syncthreads();
  float sa = part[0][l].y + part[0][64 + l].y + part[0][128 + l].y + part[0][192 + l].y;
  for (int t0 = 0; t0 < L_; t0 += 4) {
#pragma unroll
    for (int u = 0; u < 4; ++u) {
      const int t = t0 + u;
      float rl = pr[u], wl = pw[u], kl = pk[u], vl = pv[u], bl = pb[u];
      float an = pa[(u + 1) & 3];
      if (t + 4 < L_) {
        size_t a_ = base + (size_t)(t + 4) * C_;
        pr[u] = bf2f(rb[a_]); pw[u] = bf2f(wb[a_]); pk[u] = bf2f(kb[a_]);
        pv[u] = bf2f(vb[a_]); pa[u] = bf2f(ab[a_]); pb[u] = bf2f(bb[a_]);
      }
      float ew = exp2f(wl * 1.4426950408889634f);
      float po = 0.f, ps = 0.f;
#pragma unroll
      for (int i = 0; i < 16; ++i) {
        int ki = kg16 + i;
        float ewk = rlane(ew, ki), bk = rlane(bl, ki), kk = rlane(kl, ki);
        S[i] = fmaf(S[i], ewk, fmaf(bk, sa, kk * vl));
        po = fmaf(rlane(rl, ki), S[i], po);
        ps = fmaf(rlane(an, ki), S[i], ps);
      }
      part[(t + 1) & 1][kg * 64 + l] = (f32x2){po, ps};
      __syncthreads();
      f32x2 q0 = part[(t + 1) & 1][l], q1 = part[(t + 1) & 1][64 + l],
            q2 = part[(t + 1) & 1][128 + l], q3 = part[(t + 1) & 1][192 + l];
      if (kg == 0) o[base + (size_t)t * C_] = (q0.x + q1.x) + (q2.x + q3.x);
      sa = (q0.y + q1.y) + (q2.y + q3.y);
    }
  }
}

// ---------------- post-scan: GroupNorm + bonus + *g -> bf16 ----------------
__global__ __launch_bounds__(256) void k_post(
    const float* __restrict__ o, const float* __restrict__ vp, const float* __restrict__ gp,
    const float* __restrict__ dp,
    const float* __restrict__ lnw, const float* __restrict__ lnb,
    unsigned short* __restrict__ z) {
  int gw = blockIdx.x * 4 + (threadIdx.x >> 6);
  int l = threadIdx.x & 63;
  int h = gw & (H_ - 1);
  size_t bt = (size_t)(gw >> 5);
  size_t idx = bt * C_ + h * 64 + l;
  int c = h * 64 + l;
  float ov = o[idx];
  float s1 = ov;
#pragma unroll
  for (int m = 1; m < 64; m <<= 1) s1 += __shfl_xor(s1, m);
  float mu = s1 * (1.f / 64.f);
  float d = ov - mu;
  float s2 = d * d;
#pragma unroll
  for (int m = 1; m < 64; m <<= 1) s2 += __shfl_xor(s2, m);
  float var = s2 * (1.f / 64.f);
  float y = d * rsqrtf(var + 6.4e-4f);
  y = y * lnw[c] + lnb[c];
  y = fmaf(dp[bt * H_ + h], vp[idx], y);
  z[idx] = f2bf(y * gp[idx]);
}

extern "C" void kernel_launch(void* const* d_in, const int* in_sizes, int n_in,
                              void* d_out, int out_size, void* d_ws, size_t ws_size,
                              hipStream_t stream) {
  const float* x      = (const float*)d_in[0];
  const float* shift  = (const float*)d_in[1];
  const float* wkv    = (const float*)d_in[2];
  const float* vfirst = (const float*)d_in[3];
  const float* x_r    = (const float*)d_in[4];
  const float* x_w    = (const float*)d_in[5];
  const float* x_k    = (const float*)d_in[6];
  const float* x_v    = (const float*)d_in[7];
  const float* x_a    = (const float*)d_in[8];
  const float* x_g    = (const float*)d_in[9];
  const float* w0     = (const float*)d_in[10];
  const float* w1     = (const float*)d_in[11];
  const float* w2     = (const float*)d_in[12];
  const float* a0     = (const float*)d_in[13];
  const float* a1     = (const float*)d_in[14];
  const float* a2     = (const float*)d_in[15];
  const float* v0     = (const float*)d_in[16];
  const float* v1     = (const float*)d_in[17];
  const float* v2     = (const float*)d_in[18];
  const float* g1     = (const float*)d_in[19];
  const float* g2     = (const float*)d_in[20];
  const float* k_k    = (const float*)d_in[21];
  const float* k_a    = (const float*)d_in[22];
  const float* r_k    = (const float*)d_in[23];
  const float* W_r    = (const float*)d_in[24];
  const float* W_k    = (const float*)d_in[25];
  const float* W_v    = (const float*)d_in[26];
  const float* W_o    = (const float*)d_in[27];
  const float* ln_w   = (const float*)d_in[28];
  const float* ln_b   = (const float*)d_in[29];

  // ---- workspace plan: ~213 MiB (same footprint as passing R5) ----
  char* wp = (char*)d_ws;
  auto alloc = [&](size_t bytes) { char* p = wp; wp += (bytes + 255) & ~(size_t)255; return p; };
  const size_t SB = BTC_ * 2;
  const size_t SF = BTC_ * 4;

  unsigned short* w1t = (unsigned short*)alloc((size_t)C_ * 64 * 2);
  unsigned short* w2t = (unsigned short*)alloc((size_t)C_ * 64 * 2);
  unsigned short* a1t = (unsigned short*)alloc((size_t)C_ * 64 * 2);
  unsigned short* a2t = (unsigned short*)alloc((size_t)C_ * 64 * 2);
  unsigned short* v1t = (unsigned short*)alloc((size_t)C_ * 32 * 2);
  unsigned short* v2t = (unsigned short*)alloc((size_t)C_ * 32 * 2);
  unsigned short* g1t = (unsigned short*)alloc((size_t)C_ * 128 * 2);
  unsigned short* g2t = (unsigned short*)alloc((size_t)C_ * 128 * 2);
  unsigned short* hw  = (unsigned short*)alloc((size_t)BT_ * 64 * 2);
  unsigned short* ha  = (unsigned short*)alloc((size_t)BT_ * 64 * 2);
  unsigned short* hv  = (unsigned short*)alloc((size_t)BT_ * 32 * 2);
  unsigned short* hg  = (unsigned short*)alloc((size_t)BT_ * 128 * 2);
  unsigned short* Wt2 = (unsigned short*)alloc((size_t)C_ * C_ * 2 * 2); // hi|lo; later Scg
  float* dp           = (float*)alloc((size_t)BT_ * H_ * 4);
  unsigned short* xw  = (unsigned short*)alloc(SB);
  unsigned short* xa  = (unsigned short*)alloc(SB);
  unsigned short* xg  = (unsigned short*)alloc(SB);
  unsigned short* xr2 = (unsigned short*)alloc(2 * SB); // -> kbuf f32 -> Pg|Ug -> zbuf
  unsigned short* xk2 = (unsigned short*)alloc(2 * SB); // -> vbuf f32
  unsigned short* xv2 = (unsigned short*)alloc(2 * SB); // -> scan rb|kb
  float* rbuf         = (float*)alloc(SF);              // r f32 -> g f32
  unsigned short* vbb = (unsigned short*)alloc(SB);

  unsigned short* Wh = Wt2;
  unsigned short* Wl = Wt2 + (size_t)C_ * C_;
  unsigned short* xr_h = xr2, *xr_l = xr2 + BTC_;
  unsigned short* xk_h = xk2, *xk_l = xk2 + BTC_;
  unsigned short* xv_h = xv2, *xv_l = xv2 + BTC_;
  float* kbuf = (float*)xr2;
  float* vbuf = (float*)xk2;
  unsigned short* rb = xv2;
  unsigned short* kb = xv2 + BTC_;
  float* gfull = rbuf;
  unsigned short* zbuf = (unsigned short*)xr2;
  float* Pg  = (float*)xr2;                       // 16 MiB (kbuf dead after k_pre)
  float* Ug  = Pg + (size_t)1024 * 4096;          // 16 MiB
  float* Scg = (float*)Wt2;                       // 16 MiB (Wt2 dead after W_v gemm)

  float* outp  = (float*)d_out;
  float* xlast = outp + BTC_;
  float* soutp = outp + BTC_ + (size_t)B_ * C_;
  float* obuf  = outp;

  auto tr = [&](const float* in, unsigned short* out, int R, int Cc) {
    k_tr<<<dim3(Cc / 32, R / 32), 256, 0, stream>>>(in, out, R, Cc);
  };
  auto gemm = [&](const unsigned short* X, const unsigned short* Wtp, void* out,
                  int M, int N, int K, int mode) {
    k_gemm<<<dim3((N + 127) / 128, M / 128), 256, 0, stream>>>(X, Wtp, out, M, N, K, mode);
  };
  auto gemm2 = [&](const unsigned short* Xh_, const unsigned short* Xl_, int xlo,
                   const unsigned short* Wh_, const unsigned short* Wl_, int wlo,
                   void* out, int M, int N, int K, int mode) {
    k_gemm2<<<dim3((N + 127) / 128, M / 128), 256, 0, stream>>>(Xh_, Xl_, xlo, Wh_, Wl_, wlo,
                                                                out, M, N, K, mode);
  };

  k_mix<<<(int)(BTC_ / 4 / 256), 256, 0, stream>>>(x, shift, x_r, x_w, x_k, x_v, x_a, x_g,
                                                   xr_h, xr_l, xk_h, xk_l, xv_h, xv_l,
                                                   xw, xa, xg, xlast);
  tr(w1, w1t, C_, 64);  tr(w2, w2t, 64, C_);
  tr(a1, a1t, C_, 64);  tr(a2, a2t, 64, C_);
  tr(v1, v1t, C_, 32);  tr(v2, v2t, 32, C_);
  tr(g1, g1t, C_, 128); tr(g2, g2t, 128, C_);

  // LoRA stage 1
  gemm(xw, w1t, hw, BT_, 64, C_, 2);
  gemm(xa, a1t, ha, BT_, 64, C_, 1);
  gemm2(xv_h, xv_l, 1, v1t, nullptr, 0, hv, BT_, 32, C_, 1);
  gemm(xg, g1t, hg, BT_, 128, C_, 3);

  // big projections, split precision
  k_trs<<<dim3(C_ / 32, C_ / 32), 256, 0, stream>>>(W_r, Wh, Wl, C_, C_);
  gemm2(xr_h, xr_l, 1, Wh, Wl, 1, rbuf, BT_, C_, C_, 0);
  k_trs<<<dim3(C_ / 32, C_ / 32), 256, 0, stream>>>(W_k, Wh, Wl, C_, C_);
  gemm2(xk_h, xk_l, 1, Wh, Wl, 1, kbuf, BT_, C_, C_, 0);
  k_trs<<<dim3(C_ / 32, C_ / 32), 256, 0, stream>>>(W_v, Wh, Wl, C_, C_);
  gemm2(xv_h, xv_l, 1, Wh, Wl, 1, vbuf, BT_, C_, C_, 0);

  // LoRA stage 2 into dead mix buffers
  gemm(hw, w2t, xw, BT_, C_, 64, 1);
  gemm(ha, a2t, xa, BT_, C_, 64, 1);
  gemm(hv, v2t, xg, BT_, C_, 32, 1);

  k_pre<<<BT_ * H_ / 4, 256, 0, stream>>>(rbuf, kbuf, vbuf, xw, xa, xg, vfirst,
                                          w0, a0, v0, k_k, k_a, r_k,
                                          rb, xw, kb, vbb, xa, xg, dp);

  gemm(hg, g2t, gfull, BT_, C_, 128, 0);

  // chunk-parallel scan (operands: r=rb, w=xw, k=kb, v=vbb, a=xa, b=xg)
  k_scanP<<<B_ * H_ * NC_, 256, 0, stream>>>(xw, kb, vbb, xa, xg, Pg, Ug);
  k_scanC<<<B_ * H_, 256, 0, stream>>>(Pg, Ug, wkv, Scg, soutp);
  k_scanR<<<B_ * H_ * NC_, 256, 0, stream>>>(rb, xw, kb, vbb, xa, xg, Scg, obuf);

  k_post<<<BT_ * H_ / 4, 256, 0, stream>>>(obuf, vbuf, gfull, dp, ln_w, ln_b, zbuf);

  tr(W_o, Wh, C_, C_);
  gemm(zbuf, Wh, outp, BT_, C_, C_, 0);
}

// Round 7
// 1636.754 us; speedup vs baseline: 2.0782x; 1.1981x over previous
//
#include <hip/hip_runtime.h>
#include <cstdint>
#include <cmath>

#define B_ 2
#define T_ 2048
#define C_ 2048
#define H_ 32
#define BT_ (B_ * T_)
#define BTC_ ((size_t)B_ * T_ * C_)
#define L_ 128
#define NC_ 16

typedef __attribute__((ext_vector_type(4))) float f32x4;
typedef __attribute__((ext_vector_type(2))) float f32x2;
typedef __attribute__((ext_vector_type(8))) short bf16x8;
typedef __attribute__((ext_vector_type(4))) unsigned short us4;
typedef __attribute__((ext_vector_type(4))) int i32x4;

__device__ __forceinline__ unsigned short f2bf(float f) {
  union { float f; unsigned int u; } c; c.f = f;
  unsigned int u = c.u;
  return (unsigned short)((u + 0x7FFFu + ((u >> 16) & 1u)) >> 16);
}
__device__ __forceinline__ float bf2f(unsigned short h) {
  union { unsigned int u; float f; } c; c.u = ((unsigned int)h) << 16;
  return c.f;
}
__device__ __forceinline__ float rlane(float v, int lane) {
  return __int_as_float(__builtin_amdgcn_readlane(__float_as_int(v), lane));
}
__device__ __forceinline__ void split4(f32x4 v, us4& h, us4& l) {
  h.x = f2bf(v.x); l.x = f2bf(v.x - bf2f(h.x));
  h.y = f2bf(v.y); l.y = f2bf(v.y - bf2f(h.y));
  h.z = f2bf(v.z); l.z = f2bf(v.z - bf2f(h.z));
  h.w = f2bf(v.w); l.w = f2bf(v.w - bf2f(h.w));
}
// async global->LDS, 16 B per lane; LDS dest = wave-uniform base + lane*16
__device__ __forceinline__ void g2l(const void* g, void* l) {
  __builtin_amdgcn_global_load_lds((const __attribute__((address_space(1))) void*)g,
                                   (__attribute__((address_space(3))) void*)l, 16, 0, 0);
}

// ---------------- token shift + mixes: r/k/v as bf16 hi+lo pairs, w/a/g bf16 ----------------
__global__ __launch_bounds__(256) void k_mix(
    const float* __restrict__ x, const float* __restrict__ shift,
    const float* __restrict__ m_r, const float* __restrict__ m_w,
    const float* __restrict__ m_k, const float* __restrict__ m_v,
    const float* __restrict__ m_a, const float* __restrict__ m_g,
    unsigned short* __restrict__ r_h, unsigned short* __restrict__ r_l,
    unsigned short* __restrict__ k_h, unsigned short* __restrict__ k_l,
    unsigned short* __restrict__ v_h, unsigned short* __restrict__ v_l,
    unsigned short* __restrict__ o_w, unsigned short* __restrict__ o_a,
    unsigned short* __restrict__ o_g,
    float* __restrict__ xlast) {
  size_t i4 = ((size_t)blockIdx.x * 256 + threadIdx.x) * 4;
  int c = (int)(i4 % C_);
  size_t bt = i4 / C_;
  int t = (int)(bt % T_);
  int b = (int)(bt / T_);
  f32x4 xv = *(const f32x4*)(x + i4);
  f32x4 pv = (t == 0) ? *(const f32x4*)(shift + (size_t)b * C_ + c)
                      : *(const f32x4*)(x + i4 - C_);
  f32x4 dx = pv - xv;
#define MIXHL(mp, oh, ol) { f32x4 mm = *(const f32x4*)(mp + c); f32x4 rr = xv + dx * mm; \
    us4 hh, ll; split4(rr, hh, ll); *(us4*)(oh + i4) = hh; *(us4*)(ol + i4) = ll; }
#define MIXH(mp, oh) { f32x4 mm = *(const f32x4*)(mp + c); f32x4 rr = xv + dx * mm; \
    us4 pk; pk.x = f2bf(rr.x); pk.y = f2bf(rr.y); pk.z = f2bf(rr.z); pk.w = f2bf(rr.w); \
    *(us4*)(oh + i4) = pk; }
  MIXHL(m_r, r_h, r_l) MIXHL(m_k, k_h, k_l) MIXHL(m_v, v_h, v_l)
  MIXH(m_w, o_w) MIXH(m_a, o_a) MIXH(m_g, o_g)
#undef MIXHL
#undef MIXH
  if (t == T_ - 1) *(f32x4*)(xlast + (size_t)b * C_ + c) = xv;
}

// ---------------- f32 [R][Cc] -> bf16 [Cc][R] transpose ----------------
__global__ __launch_bounds__(256) void k_tr(const float* __restrict__ in,
                                            unsigned short* __restrict__ out,
                                            int R, int Cc) {
  __shared__ float tile[32][33];
  int c0 = blockIdx.x * 32, r0 = blockIdx.y * 32;
  int tid = threadIdx.x;
  int rr = tid >> 3, c4 = (tid & 7) * 4;
  f32x4 v = *(const f32x4*)(in + (size_t)(r0 + rr) * Cc + c0 + c4);
  tile[rr][c4] = v.x; tile[rr][c4 + 1] = v.y; tile[rr][c4 + 2] = v.z; tile[rr][c4 + 3] = v.w;
  __syncthreads();
  int cc = tid >> 3, r4 = (tid & 7) * 4;
  us4 o;
  o.x = f2bf(tile[r4][cc]); o.y = f2bf(tile[r4 + 1][cc]);
  o.z = f2bf(tile[r4 + 2][cc]); o.w = f2bf(tile[r4 + 3][cc]);
  *(us4*)(out + (size_t)(c0 + cc) * R + r0 + r4) = o;
}

// ---------------- f32 [R][Cc] -> bf16 hi+lo [Cc][R] split transpose ----------------
__global__ __launch_bounds__(256) void k_trs(const float* __restrict__ in,
                                             unsigned short* __restrict__ oh,
                                             unsigned short* __restrict__ ol,
                                             int R, int Cc) {
  __shared__ float tile[32][33];
  int c0 = blockIdx.x * 32, r0 = blockIdx.y * 32;
  int tid = threadIdx.x;
  int rr = tid >> 3, c4 = (tid & 7) * 4;
  f32x4 v = *(const f32x4*)(in + (size_t)(r0 + rr) * Cc + c0 + c4);
  tile[rr][c4] = v.x; tile[rr][c4 + 1] = v.y; tile[rr][c4 + 2] = v.z; tile[rr][c4 + 3] = v.w;
  __syncthreads();
  int cc = tid >> 3, r4 = (tid & 7) * 4;
  f32x4 w = { tile[r4][cc], tile[r4 + 1][cc], tile[r4 + 2][cc], tile[r4 + 3][cc] };
  us4 h, l; split4(w, h, l);
  size_t o = (size_t)(c0 + cc) * R + r0 + r4;
  *(us4*)(oh + o) = h; *(us4*)(ol + o) = l;
}

// ---------------- bf16 GEMM: C[M,N] = X[M,K] @ Wt[N,K]^T (global_load_lds staging) ----------------
__global__ __launch_bounds__(256) void k_gemm(
    const unsigned short* __restrict__ X, const unsigned short* __restrict__ Wt,
    void* __restrict__ out, int M, int N, int K, int mode) {
  __shared__ alignas(16) unsigned short As[128 * 32];
  __shared__ alignas(16) unsigned short Bs[128 * 32];
  const int tid = threadIdx.x;
  const int lane = tid & 63, wave = tid >> 6;
  const int wr = wave >> 1, wc = wave & 1;
  const int lm = lane & 15, lq = lane >> 4;
  const int m0 = blockIdx.y * 128, n0 = blockIdx.x * 128;
  const int srow = (lane >> 2);
  const int kcol = (lane & 3) * 8;
  f32x4 acc[4][4];
#pragma unroll
  for (int i = 0; i < 4; ++i)
#pragma unroll
    for (int j = 0; j < 4; ++j) acc[i][j] = (f32x4){0.f, 0.f, 0.f, 0.f};

  for (int k0 = 0; k0 < K; k0 += 32) {
#pragma unroll
    for (int p = 0; p < 2; ++p) {
      int row = wave * 32 + p * 16 + srow;
      g2l(X + (size_t)(m0 + row) * K + k0 + kcol, As + (wave * 2 + p) * 512);
      int n = n0 + row; if (n > N - 1) n = N - 1;
      g2l(Wt + (size_t)n * K + k0 + kcol, Bs + (wave * 2 + p) * 512);
    }
    __syncthreads();
    bf16x8 af[4], bfr[4];
#pragma unroll
    for (int i = 0; i < 4; ++i)
      af[i] = *(const bf16x8*)(As + (size_t)(wr * 64 + i * 16 + lm) * 32 + lq * 8);
#pragma unroll
    for (int j = 0; j < 4; ++j)
      bfr[j] = *(const bf16x8*)(Bs + (size_t)(wc * 64 + j * 16 + lm) * 32 + lq * 8);
#pragma unroll
    for (int i = 0; i < 4; ++i)
#pragma unroll
      for (int j = 0; j < 4; ++j)
        acc[i][j] = __builtin_amdgcn_mfma_f32_16x16x32_bf16(af[i], bfr[j], acc[i][j], 0, 0, 0);
    __syncthreads();
  }
#pragma unroll
  for (int i = 0; i < 4; ++i)
#pragma unroll
    for (int j = 0; j < 4; ++j) {
      int n = n0 + wc * 64 + j * 16 + lm;
      if (n >= N) continue;
      int mb = m0 + wr * 64 + i * 16 + lq * 4;
#pragma unroll
      for (int r = 0; r < 4; ++r) {
        float val = acc[i][j][r];
        size_t off = (size_t)(mb + r) * N + n;
        if (mode == 0) {
          ((float*)out)[off] = val;
        } else {
          if (mode == 2) val = tanhf(val);
          else if (mode == 3) val = 1.0f / (1.0f + __expf(-val));
          ((unsigned short*)out)[off] = f2bf(val);
        }
      }
    }
}

// ---------------- split (hi+lo) bf16 GEMM: hh + lh + hl (ll dropped, ~2^-17 rel) ----------------
__global__ __launch_bounds__(256) void k_gemm2(
    const unsigned short* __restrict__ Xh, const unsigned short* __restrict__ Xl, int xlo,
    const unsigned short* __restrict__ Wh, const unsigned short* __restrict__ Wl, int wlo,
    void* __restrict__ out, int M, int N, int K, int mode) {
  __shared__ alignas(16) unsigned short Ah[128 * 32];
  __shared__ alignas(16) unsigned short Al[128 * 32];
  __shared__ alignas(16) unsigned short Bh[128 * 32];
  __shared__ alignas(16) unsigned short Bl[128 * 32];
  const int tid = threadIdx.x;
  const int lane = tid & 63, wave = tid >> 6;
  const int wr = wave >> 1, wc = wave & 1;
  const int lm = lane & 15, lq = lane >> 4;
  const int m0 = blockIdx.y * 128, n0 = blockIdx.x * 128;
  const int srow = (lane >> 2);
  const int kcol = (lane & 3) * 8;
  f32x4 acc[4][4];
#pragma unroll
  for (int i = 0; i < 4; ++i)
#pragma unroll
    for (int j = 0; j < 4; ++j) acc[i][j] = (f32x4){0.f, 0.f, 0.f, 0.f};

  for (int k0 = 0; k0 < K; k0 += 32) {
#pragma unroll
    for (int p = 0; p < 2; ++p) {
      int row = wave * 32 + p * 16 + srow;
      int off = (wave * 2 + p) * 512;
      size_t ga = (size_t)(m0 + row) * K + k0 + kcol;
      g2l(Xh + ga, Ah + off);
      if (xlo) g2l(Xl + ga, Al + off);
      int n = n0 + row; if (n > N - 1) n = N - 1;
      size_t gb = (size_t)n * K + k0 + kcol;
      g2l(Wh + gb, Bh + off);
      if (wlo) g2l(Wl + gb, Bl + off);
    }
    __syncthreads();
    bf16x8 ah[4], bh[4];
#pragma unroll
    for (int i = 0; i < 4; ++i)
      ah[i] = *(const bf16x8*)(Ah + (size_t)(wr * 64 + i * 16 + lm) * 32 + lq * 8);
#pragma unroll
    for (int j = 0; j < 4; ++j)
      bh[j] = *(const bf16x8*)(Bh + (size_t)(wc * 64 + j * 16 + lm) * 32 + lq * 8);
#pragma unroll
    for (int i = 0; i < 4; ++i)
#pragma unroll
      for (int j = 0; j < 4; ++j)
        acc[i][j] = __builtin_amdgcn_mfma_f32_16x16x32_bf16(ah[i], bh[j], acc[i][j], 0, 0, 0);
    if (xlo) {
      bf16x8 al[4];
#pragma unroll
      for (int i = 0; i < 4; ++i)
        al[i] = *(const bf16x8*)(Al + (size_t)(wr * 64 + i * 16 + lm) * 32 + lq * 8);
#pragma unroll
      for (int i = 0; i < 4; ++i)
#pragma unroll
        for (int j = 0; j < 4; ++j)
          acc[i][j] = __builtin_amdgcn_mfma_f32_16x16x32_bf16(al[i], bh[j], acc[i][j], 0, 0, 0);
    }
    if (wlo) {
      bf16x8 bl[4];
#pragma unroll
      for (int j = 0; j < 4; ++j)
        bl[j] = *(const bf16x8*)(Bl + (size_t)(wc * 64 + j * 16 + lm) * 32 + lq * 8);
#pragma unroll
      for (int i = 0; i < 4; ++i)
#pragma unroll
        for (int j = 0; j < 4; ++j)
          acc[i][j] = __builtin_amdgcn_mfma_f32_16x16x32_bf16(ah[i], bl[j], acc[i][j], 0, 0, 0);
    }
    __syncthreads();
  }
#pragma unroll
  for (int i = 0; i < 4; ++i)
#pragma unroll
    for (int j = 0; j < 4; ++j) {
      int n = n0 + wc * 64 + j * 16 + lm;
      if (n >= N) continue;
      int mb = m0 + wr * 64 + i * 16 + lq * 4;
#pragma unroll
      for (int r = 0; r < 4; ++r) {
        float val = acc[i][j][r];
        size_t off = (size_t)(mb + r) * N + n;
        if (mode == 0) {
          ((float*)out)[off] = val;
        } else {
          if (mode == 2) val = tanhf(val);
          else if (mode == 3) val = 1.0f / (1.0f + __expf(-val));
          ((unsigned short*)out)[off] = f2bf(val);
        }
      }
    }
}

// ---------------- pre-scan fused elementwise ----------------
__global__ __launch_bounds__(256) void k_pre(
    const float* __restrict__ rp, const float* __restrict__ kp, float* __restrict__ vp,
    const unsigned short* __restrict__ ww, const unsigned short* __restrict__ aa,
    const unsigned short* __restrict__ vv,
    const float* __restrict__ vfirst,
    const float* __restrict__ w0, const float* __restrict__ a0, const float* __restrict__ v0,
    const float* __restrict__ kkc, const float* __restrict__ kac,
    const float* __restrict__ rkw,
    unsigned short* __restrict__ rb, unsigned short* __restrict__ wb,
    unsigned short* __restrict__ kb, unsigned short* __restrict__ vb,
    unsigned short* __restrict__ ab, unsigned short* __restrict__ bb,
    float* __restrict__ dp) {
  int gw = blockIdx.x * 4 + (threadIdx.x >> 6);
  int l = threadIdx.x & 63;
  int h = gw & (H_ - 1);
  size_t bt = (size_t)(gw >> 5);
  size_t idx = bt * C_ + h * 64 + l;
  int c = h * 64 + l;
  float rf = rp[idx], kf = kp[idx], vr = vp[idx];
  float z = -(w0[c] + bf2f(ww[idx]));
  float sp = (z > 15.f) ? z : log1pf(__expf(z));
  float wv = -sp - 0.5f;
  float ag = 1.f / (1.f + __expf(-(a0[c] + bf2f(aa[idx]))));
  float sv = 1.f / (1.f + __expf(-(v0[c] + bf2f(vv[idx]))));
  float vf = vr + (vfirst[idx] - vr) * sv;
  float kkv = kf * kkc[c];
  float ss = kkv * kkv;
#pragma unroll
  for (int m = 1; m < 64; m <<= 1) ss += __shfl_xor(ss, m);
  float nrm = fmaxf(sqrtf(ss), 1e-12f);
  float kkn = kkv / nrm;
  float ks = kf * (1.f + (ag - 1.f) * kac[c]);
  vp[idx] = vf;
  float bon = rf * ks * rkw[c];
#pragma unroll
  for (int m = 1; m < 64; m <<= 1) bon += __shfl_xor(bon, m);
  if (l == 0) dp[bt * H_ + h] = bon;
  rb[idx] = f2bf(rf); wb[idx] = f2bf(wv); kb[idx] = f2bf(ks);
  vb[idx] = f2bf(vf); ab[idx] = f2bf(-kkn); bb[idx] = f2bf(kkn * ag);
}

// ================= chunk-parallel scan =================
__global__ __launch_bounds__(256) void k_scanP(
    const unsigned short* __restrict__ wb, const unsigned short* __restrict__ kb,
    const unsigned short* __restrict__ vb, const unsigned short* __restrict__ ab,
    const unsigned short* __restrict__ bb,
    float* __restrict__ Pg, float* __restrict__ Ug) {
  const int blk = blockIdx.x;
  const int c = blk & (NC_ - 1), bh = blk >> 4;
  const int b = bh >> 5, h = bh & (H_ - 1);
  const int l = threadIdx.x & 63;
  const int kg = __builtin_amdgcn_readfirstlane(threadIdx.x >> 6);
  const int kg16 = kg * 16;
  __shared__ f32x2 part[2][256];
  size_t base = (size_t)b * ((size_t)T_ * C_) + (size_t)(c * L_) * C_ + h * 64 + l;
  float P[16], U[16];
#pragma unroll
  for (int i = 0; i < 16; ++i) { P[i] = (kg16 + i == l) ? 1.f : 0.f; U[i] = 0.f; }
  float pw[4], pk[4], pv[4], pa[4], pb[4];
#pragma unroll
  for (int s = 0; s < 4; ++s) {
    size_t a_ = base + (size_t)s * C_;
    pw[s] = bf2f(wb[a_]); pk[s] = bf2f(kb[a_]); pv[s] = bf2f(vb[a_]);
    pa[s] = bf2f(ab[a_]); pb[s] = bf2f(bb[a_]);
  }
  float saP = pa[0];
  float saU = 0.f;
  for (int t0 = 0; t0 < L_; t0 += 4) {
#pragma unroll
    for (int u = 0; u < 4; ++u) {
      const int t = t0 + u;
      float wl = pw[u], kl = pk[u], vl = pv[u], bl = pb[u];
      float an = pa[(u + 1) & 3];
      if (t + 4 < L_) {
        size_t a_ = base + (size_t)(t + 4) * C_;
        pw[u] = bf2f(wb[a_]); pk[u] = bf2f(kb[a_]); pv[u] = bf2f(vb[a_]);
        pa[u] = bf2f(ab[a_]); pb[u] = bf2f(bb[a_]);
      }
      float ew = exp2f(wl * 1.4426950408889634f);
      float psP = 0.f, psU = 0.f;
#pragma unroll
      for (int i = 0; i < 16; ++i) {
        int ki = kg16 + i;
        float ewk = rlane(ew, ki), bk = rlane(bl, ki), kk = rlane(kl, ki);
        P[i] = fmaf(P[i], ewk, bk * saP);
        U[i] = fmaf(U[i], ewk, fmaf(bk, saU, kk * vl));
        float ak = rlane(an, ki);
        psP = fmaf(ak, P[i], psP);
        psU = fmaf(ak, U[i], psU);
      }
      part[t & 1][kg * 64 + l] = (f32x2){psP, psU};
      __syncthreads();
      f32x2 q0 = part[t & 1][l], q1 = part[t & 1][64 + l],
            q2 = part[t & 1][128 + l], q3 = part[t & 1][192 + l];
      saP = (q0.x + q1.x) + (q2.x + q3.x);
      saU = (q0.y + q1.y) + (q2.y + q3.y);
    }
  }
  size_t pb_ = (size_t)blk * 4096;
#pragma unroll
  for (int i = 0; i < 16; ++i) {
    Pg[pb_ + (size_t)l * 64 + kg16 + i] = P[i];
    Ug[pb_ + (size_t)(kg16 + i) * 64 + l] = U[i];
  }
}

__global__ __launch_bounds__(256) void k_scanC(
    const float* __restrict__ Pg, const float* __restrict__ Ug,
    const float* __restrict__ s0, float* __restrict__ Scg, float* __restrict__ sout) {
  const int bh = blockIdx.x;
  const int l = threadIdx.x & 63;
  const int kg = __builtin_amdgcn_readfirstlane(threadIdx.x >> 6);
  const int kg16 = kg * 16;
  const int tid = threadIdx.x;
  __shared__ float Sb[4096];
#pragma unroll
  for (int q = 0; q < 4; ++q) {
    int e = tid * 16 + q * 4;
    *(f32x4*)(Sb + e) = *(const f32x4*)(s0 + (size_t)bh * 4096 + e);
  }
  __syncthreads();
  for (int c = 0; c < NC_; ++c) {
    size_t cb = ((size_t)bh * NC_ + c) * 4096;
#pragma unroll
    for (int q = 0; q < 4; ++q) {
      int e = tid * 16 + q * 4;
      *(f32x4*)(Scg + cb + e) = *(const f32x4*)(Sb + e);
    }
    const float* Pt = Pg + cb;
    const float* Uc = Ug + cb;
    float acc[16];
#pragma unroll
    for (int i = 0; i < 16; ++i) acc[i] = Uc[(size_t)(kg16 + i) * 64 + l];
    for (int j = 0; j < 64; ++j) {
      float s = Sb[j * 64 + l];
#pragma unroll
      for (int i = 0; i < 16; ++i) acc[i] = fmaf(Pt[j * 64 + kg16 + i], s, acc[i]);
    }
    __syncthreads();
#pragma unroll
    for (int i = 0; i < 16; ++i) Sb[(kg16 + i) * 64 + l] = acc[i];
    __syncthreads();
  }
#pragma unroll
  for (int q = 0; q < 4; ++q) {
    int e = tid * 16 + q * 4;
    *(f32x4*)(sout + (size_t)bh * 4096 + e) = *(const f32x4*)(Sb + e);
  }
}

__global__ __launch_bounds__(256) void k_scanR(
    const unsigned short* __restrict__ rb, const unsigned short* __restrict__ wb,
    const unsigned short* __restrict__ kb, const unsigned short* __restrict__ vb,
    const unsigned short* __restrict__ ab, const unsigned short* __restrict__ bb,
    const float* __restrict__ Scg, float* __restrict__ o) {
  const int blk = blockIdx.x;
  const int c = blk & (NC_ - 1), bh = blk >> 4;
  const int b = bh >> 5, h = bh & (H_ - 1);
  const int l = threadIdx.x & 63;
  const int kg = __builtin_amdgcn_readfirstlane(threadIdx.x >> 6);
  const int kg16 = kg * 16;
  __shared__ f32x2 part[2][256];
  size_t base = (size_t)b * ((size_t)T_ * C_) + (size_t)(c * L_) * C_ + h * 64 + l;
  float S[16];
  size_t cb = (size_t)blk * 4096;
#pragma unroll
  for (int i = 0; i < 16; ++i) S[i] = Scg[cb + (size_t)(kg16 + i) * 64 + l];
  float pr[4], pw[4], pk[4], pv[4], pa[4], pb[4];
#pragma unroll
  for (int s = 0; s < 4; ++s) {
    size_t a_ = base + (size_t)s * C_;
    pr[s] = bf2f(rb[a_]); pw[s] = bf2f(wb[a_]); pk[s] = bf2f(kb[a_]);
    pv[s] = bf2f(vb[a_]); pa[s] = bf2f(ab[a_]); pb[s] = bf2f(bb[a_]);
  }
  {
    float ps = 0.f;
#pragma unroll
    for (int i = 0; i < 16; ++i) ps = fmaf(rlane(pa[0], kg16 + i), S[i], ps);
    part[0][kg * 64 + l] = (f32x2){0.f, ps};
  }
  __syncthreads();
  float sa = part[0][l].y + part[0][64 + l].y + part[0][128 + l].y + part[0][192 + l].y;
  for (int t0 = 0; t0 < L_; t0 += 4) {
#pragma unroll
    for (int u = 0; u < 4; ++u) {
      const int t = t0 + u;
      float rl = pr[u], wl = pw[u], kl = pk[u], vl = pv[u], bl = pb[u];
      float an = pa[(u + 1) & 3];
      if (t + 4 < L_) {
        size_t a_ = base + (size_t)(t + 4) * C_;
        pr[u] = bf2f(rb[a_]); pw[u] = bf2f(wb[a_]); pk[u] = bf2f(kb[a_]);
        pv[u] = bf2f(vb[a_]); pa[u] = bf2f(ab[a_]); pb[u] = bf2f(bb[a_]);
      }
      float ew = exp2f(wl * 1.4426950408889634f);
      float po = 0.f, ps = 0.f;
#pragma unroll
      for (int i = 0; i < 16; ++i) {
        int ki = kg16 + i;
        float ewk = rlane(ew, ki), bk = rlane(bl, ki), kk = rlane(kl, ki);
        S[i] = fmaf(S[i], ewk, fmaf(bk, sa, kk * vl));
        po = fmaf(rlane(rl, ki), S[i], po);
        ps = fmaf(rlane(an, ki), S[i], ps);
      }
      part[(t + 1) & 1][kg * 64 + l] = (f32x2){po, ps};
      __syncthreads();
      f32x2 q0 = part[(t + 1) & 1][l], q1 = part[(t + 1) & 1][64 + l],
            q2 = part[(t + 1) & 1][128 + l], q3 = part[(t + 1) & 1][192 + l];
      if (kg == 0) o[base + (size_t)t * C_] = (q0.x + q1.x) + (q2.x + q3.x);
      sa = (q0.y + q1.y) + (q2.y + q3.y);
    }
  }
}

// ---------------- post-scan: GroupNorm + bonus + *g -> bf16 ----------------
__global__ __launch_bounds__(256) void k_post(
    const float* __restrict__ o, const float* __restrict__ vp, const float* __restrict__ gp,
    const float* __restrict__ dp,
    const float* __restrict__ lnw, const float* __restrict__ lnb,
    unsigned short* __restrict__ z) {
  int gw = blockIdx.x * 4 + (threadIdx.x >> 6);
  int l = threadIdx.x & 63;
  int h = gw & (H_ - 1);
  size_t bt = (size_t)(gw >> 5);
  size_t idx = bt * C_ + h * 64 + l;
  int c = h * 64 + l;
  float ov = o[idx];
  float s1 = ov;
#pragma unroll
  for (int m = 1; m < 64; m <<= 1) s1 += __shfl_xor(s1, m);
  float mu = s1 * (1.f / 64.f);
  float d = ov - mu;
  float s2 = d * d;
#pragma unroll
  for (int m = 1; m < 64; m <<= 1) s2 += __shfl_xor(s2, m);
  float var = s2 * (1.f / 64.f);
  float y = d * rsqrtf(var + 6.4e-4f);
  y = y * lnw[c] + lnb[c];
  y = fmaf(dp[bt * H_ + h], vp[idx], y);
  z[idx] = f2bf(y * gp[idx]);
}

extern "C" void kernel_launch(void* const* d_in, const int* in_sizes, int n_in,
                              void* d_out, int out_size, void* d_ws, size_t ws_size,
                              hipStream_t stream) {
  const float* x      = (const float*)d_in[0];
  const float* shift  = (const float*)d_in[1];
  const float* wkv    = (const float*)d_in[2];
  const float* vfirst = (const float*)d_in[3];
  const float* x_r    = (const float*)d_in[4];
  const float* x_w    = (const float*)d_in[5];
  const float* x_k    = (const float*)d_in[6];
  const float* x_v    = (const float*)d_in[7];
  const float* x_a    = (const float*)d_in[8];
  const float* x_g    = (const float*)d_in[9];
  const float* w0     = (const float*)d_in[10];
  const float* w1     = (const float*)d_in[11];
  const float* w2     = (const float*)d_in[12];
  const float* a0     = (const float*)d_in[13];
  const float* a1     = (const float*)d_in[14];
  const float* a2     = (const float*)d_in[15];
  const float* v0     = (const float*)d_in[16];
  const float* v1     = (const float*)d_in[17];
  const float* v2     = (const float*)d_in[18];
  const float* g1     = (const float*)d_in[19];
  const float* g2     = (const float*)d_in[20];
  const float* k_k    = (const float*)d_in[21];
  const float* k_a    = (const float*)d_in[22];
  const float* r_k    = (const float*)d_in[23];
  const float* W_r    = (const float*)d_in[24];
  const float* W_k    = (const float*)d_in[25];
  const float* W_v    = (const float*)d_in[26];
  const float* W_o    = (const float*)d_in[27];
  const float* ln_w   = (const float*)d_in[28];
  const float* ln_b   = (const float*)d_in[29];

  // ---- workspace plan: ~213 MiB (same footprint as passing R5/R6) ----
  char* wp = (char*)d_ws;
  auto alloc = [&](size_t bytes) { char* p = wp; wp += (bytes + 255) & ~(size_t)255; return p; };
  const size_t SB = BTC_ * 2;
  const size_t SF = BTC_ * 4;

  unsigned short* w1t = (unsigned short*)alloc((size_t)C_ * 64 * 2);
  unsigned short* w2t = (unsigned short*)alloc((size_t)C_ * 64 * 2);
  unsigned short* a1t = (unsigned short*)alloc((size_t)C_ * 64 * 2);
  unsigned short* a2t = (unsigned short*)alloc((size_t)C_ * 64 * 2);
  unsigned short* v1t = (unsigned short*)alloc((size_t)C_ * 32 * 2);
  unsigned short* v2t = (unsigned short*)alloc((size_t)C_ * 32 * 2);
  unsigned short* g1t = (unsigned short*)alloc((size_t)C_ * 128 * 2);
  unsigned short* g2t = (unsigned short*)alloc((size_t)C_ * 128 * 2);
  unsigned short* hw  = (unsigned short*)alloc((size_t)BT_ * 64 * 2);
  unsigned short* ha  = (unsigned short*)alloc((size_t)BT_ * 64 * 2);
  unsigned short* hv  = (unsigned short*)alloc((size_t)BT_ * 32 * 2);
  unsigned short* hg  = (unsigned short*)alloc((size_t)BT_ * 128 * 2);
  unsigned short* Wt2 = (unsigned short*)alloc((size_t)C_ * C_ * 2 * 2); // hi|lo; later Scg
  float* dp           = (float*)alloc((size_t)BT_ * H_ * 4);
  unsigned short* xw  = (unsigned short*)alloc(SB);
  unsigned short* xa  = (unsigned short*)alloc(SB);
  unsigned short* xg  = (unsigned short*)alloc(SB);
  unsigned short* xr2 = (unsigned short*)alloc(2 * SB); // -> kbuf f32 -> Pg|Ug -> zbuf
  unsigned short* xk2 = (unsigned short*)alloc(2 * SB); // -> vbuf f32
  unsigned short* xv2 = (unsigned short*)alloc(2 * SB); // -> scan rb|kb
  float* rbuf         = (float*)alloc(SF);              // r f32 -> g f32
  unsigned short* vbb = (unsigned short*)alloc(SB);

  unsigned short* Wh = Wt2;
  unsigned short* Wl = Wt2 + (size_t)C_ * C_;
  unsigned short* xr_h = xr2, *xr_l = xr2 + BTC_;
  unsigned short* xk_h = xk2, *xk_l = xk2 + BTC_;
  unsigned short* xv_h = xv2, *xv_l = xv2 + BTC_;
  float* kbuf = (float*)xr2;
  float* vbuf = (float*)xk2;
  unsigned short* rb = xv2;
  unsigned short* kb = xv2 + BTC_;
  float* gfull = rbuf;
  unsigned short* zbuf = (unsigned short*)xr2;
  float* Pg  = (float*)xr2;
  float* Ug  = Pg + (size_t)1024 * 4096;
  float* Scg = (float*)Wt2;

  float* outp  = (float*)d_out;
  float* xlast = outp + BTC_;
  float* soutp = outp + BTC_ + (size_t)B_ * C_;
  float* obuf  = outp;

  auto tr = [&](const float* in, unsigned short* out, int R, int Cc) {
    k_tr<<<dim3(Cc / 32, R / 32), 256, 0, stream>>>(in, out, R, Cc);
  };
  auto gemm = [&](const unsigned short* X, const unsigned short* Wtp, void* out,
                  int M, int N, int K, int mode) {
    k_gemm<<<dim3((N + 127) / 128, M / 128), 256, 0, stream>>>(X, Wtp, out, M, N, K, mode);
  };
  auto gemm2 = [&](const unsigned short* Xh_, const unsigned short* Xl_, int xlo,
                   const unsigned short* Wh_, const unsigned short* Wl_, int wlo,
                   void* out, int M, int N, int K, int mode) {
    k_gemm2<<<dim3((N + 127) / 128, M / 128), 256, 0, stream>>>(Xh_, Xl_, xlo, Wh_, Wl_, wlo,
                                                                out, M, N, K, mode);
  };

  k_mix<<<(int)(BTC_ / 4 / 256), 256, 0, stream>>>(x, shift, x_r, x_w, x_k, x_v, x_a, x_g,
                                                   xr_h, xr_l, xk_h, xk_l, xv_h, xv_l,
                                                   xw, xa, xg, xlast);
  tr(w1, w1t, C_, 64);  tr(w2, w2t, 64, C_);
  tr(a1, a1t, C_, 64);  tr(a2, a2t, 64, C_);
  tr(v1, v1t, C_, 32);  tr(v2, v2t, 32, C_);
  tr(g1, g1t, C_, 128); tr(g2, g2t, 128, C_);

  // LoRA stage 1
  gemm(xw, w1t, hw, BT_, 64, C_, 2);
  gemm(xa, a1t, ha, BT_, 64, C_, 1);
  gemm2(xv_h, xv_l, 1, v1t, nullptr, 0, hv, BT_, 32, C_, 1);
  gemm(xg, g1t, hg, BT_, 128, C_, 3);

  // big projections, split precision (hh + lh + hl)
  k_trs<<<dim3(C_ / 32, C_ / 32), 256, 0, stream>>>(W_r, Wh, Wl, C_, C_);
  gemm2(xr_h, xr_l, 1, Wh, Wl, 1, rbuf, BT_, C_, C_, 0);
  k_trs<<<dim3(C_ / 32, C_ / 32), 256, 0, stream>>>(W_k, Wh, Wl, C_, C_);
  gemm2(xk_h, xk_l, 1, Wh, Wl, 1, kbuf, BT_, C_, C_, 0);
  k_trs<<<dim3(C_ / 32, C_ / 32), 256, 0, stream>>>(W_v, Wh, Wl, C_, C_);
  gemm2(xv_h, xv_l, 1, Wh, Wl, 1, vbuf, BT_, C_, C_, 0);

  // LoRA stage 2 into dead mix buffers
  gemm(hw, w2t, xw, BT_, C_, 64, 1);
  gemm(ha, a2t, xa, BT_, C_, 64, 1);
  gemm(hv, v2t, xg, BT_, C_, 32, 1);

  k_pre<<<BT_ * H_ / 4, 256, 0, stream>>>(rbuf, kbuf, vbuf, xw, xa, xg, vfirst,
                                          w0, a0, v0, k_k, k_a, r_k,
                                          rb, xw, kb, vbb, xa, xg, dp);

  gemm(hg, g2t, gfull, BT_, C_, 128, 0);

  // chunk-parallel scan
  k_scanP<<<B_ * H_ * NC_, 256, 0, stream>>>(xw, kb, vbb, xa, xg, Pg, Ug);
  k_scanC<<<B_ * H_, 256, 0, stream>>>(Pg, Ug, wkv, Scg, soutp);
  k_scanR<<<B_ * H_ * NC_, 256, 0, stream>>>(rb, xw, kb, vbb, xa, xg, Scg, obuf);

  k_post<<<BT_ * H_ / 4, 256, 0, stream>>>(obuf, vbuf, gfull, dp, ln_w, ln_b, zbuf);

  tr(W_o, Wh, C_, C_);
  gemm(zbuf, Wh, outp, BT_, C_, C_, 0);
}